// Round 15
// baseline (296.973 us; speedup 1.0000x reference)
//
#include <hip/hip_runtime.h>

#define NC 200000
#define NM 50000
#define NE 1000000
#define DF 64   // feature dim (D == H == 64)

#define BSH 10
#define BW 1024
#define NBM ((NM + BW - 1) >> BSH)   // 49
#define NBC ((NC + BW - 1) >> BSH)   // 196
#define CH 4096                      // edges per chunk block
#define NSB ((NE + CH - 1) / CH)     // 245
#define PSB 1024                     // presplit blocks inside prep_k

typedef __attribute__((ext_vector_type(8))) short bf16x8;
typedef __attribute__((ext_vector_type(4))) float f32x4;
typedef __attribute__((ext_vector_type(4))) unsigned short u16x4;

// ---------------- round-to-nearest bf16 helpers ----------------
__device__ __forceinline__ short bf16rn(float x) {
    unsigned u = __builtin_bit_cast(unsigned, x);
    unsigned r = u + 0x7FFFu + ((u >> 16) & 1u);
    return (short)(r >> 16);
}
__device__ __forceinline__ float bf16f(short h) {
    unsigned u = ((unsigned)(unsigned short)h) << 16;
    return __builtin_bit_cast(float, u);
}
__device__ __forceinline__ void split8(const f32x4 u, const f32x4 v,
                                       bf16x8& hi, bf16x8& lo) {
#pragma unroll
    for (int b = 0; b < 4; ++b) {
        short h = bf16rn(u[b]);
        hi[b] = h;
        lo[b] = bf16rn(u[b] - bf16f(h));
    }
#pragma unroll
    for (int b = 0; b < 4; ++b) {
        short h = bf16rn(v[b]);
        hi[4 + b] = h;
        lo[4 + b] = bf16rn(v[b] - bf16f(h));
    }
}

// ---------------- wave-wide inclusive scan (64 lanes, no barriers) ----------------
__device__ __forceinline__ int wscan_incl(int v, int lane) {
#pragma unroll
    for (int off = 1; off < 64; off <<= 1) {
        int y = __shfl_up(v, off);
        if (lane >= off) v += y;
    }
    return v;
}

// ---- prep: coarse hists (no global atomics) + bf16 presplit + W_lin folding ------
__global__ __launch_bounds__(256) void prep_k(const int* __restrict__ cm_dst,
                                              const int* __restrict__ mc_dst,
                                              int* __restrict__ pmM,
                                              int* __restrict__ pmC,
                                              const float* __restrict__ x_c,
                                              const float* __restrict__ x_m,
                                              u16x4* __restrict__ xc16,
                                              u16x4* __restrict__ xm16,
                                              const float* __restrict__ Wl2,
                                              const float* __restrict__ Wr2,
                                              const float* __restrict__ b2,
                                              const float* __restrict__ Wlin,
                                              const float* __restrict__ blin,
                                              float* __restrict__ Vl,
                                              float* __restrict__ Vr,
                                              float* __restrict__ bo) {
    __shared__ int cnt[256];
    const int t = threadIdx.x;
    if (blockIdx.x < 2 * NSB) {
        const int side = (blockIdx.x >= NSB);
        const int blk = blockIdx.x - side * NSB;
        const int* dst = side ? mc_dst : cm_dst;
        int* pm = side ? pmC : pmM;
        const int nb = side ? NBC : NBM;
        cnt[t] = 0;
        __syncthreads();
        const int e0 = blk * CH;
        const int n = min(CH, NE - e0);
        for (int i = t; i < n; i += 256) atomicAdd(&cnt[dst[e0 + i] >> BSH], 1);
        __syncthreads();
        if (t < nb) pm[(long)blk * nb + t] = cnt[t];
    } else if (blockIdx.x < 2 * NSB + PSB) {
        const int blk = blockIdx.x - 2 * NSB;
        const int NC4 = NC * (DF / 4);
        const int NT4 = (NC + NM) * (DF / 4);
        const int st = PSB * 256;
        for (int i = blk * 256 + t; i < NT4; i += st) {
            const bool isc = (i < NC4);
            const int j = isc ? i : i - NC4;
            const f32x4 v = isc ? ((const f32x4*)x_c)[j] : ((const f32x4*)x_m)[j];
            u16x4 o;
#pragma unroll
            for (int b = 0; b < 4; ++b) o[b] = (unsigned short)bf16rn(v[b]);
            if (isc) xc16[j] = o;
            else     xm16[j] = o;
        }
    } else {
        // compose Vl = Wl2@Wlin, Vr = Wr2@Wlin (64x2 padded to 64x16), bo = b2@Wlin+blin
        for (int i = t; i < 2 * 64 * 16; i += 256) {
            float* dst = (i < 1024) ? Vl : Vr;
            dst[i & 1023] = 0.0f;
        }
        __syncthreads();
        if (t < 128) {
            const int k = t >> 1, o = t & 1;
            float sl = 0.f, sr = 0.f;
            for (int j = 0; j < 64; ++j) {
                sl += Wl2[k * 64 + j] * Wlin[j * 2 + o];
                sr += Wr2[k * 64 + j] * Wlin[j * 2 + o];
            }
            Vl[k * 16 + o] = sl;
            Vr[k * 16 + o] = sr;
        }
        if (t < 2) {
            float s = blin[t];
            for (int j = 0; j < 64; ++j) s += b2[j] * Wlin[j * 2 + t];
            bo[t] = s;
        }
    }
}

// ---------------- coarse reduce+scan (one tiny block): cstart + ccur init ----------
__global__ __launch_bounds__(256) void cscan2_k(const int* __restrict__ pmM,
                                                const int* __restrict__ pmC,
                                                int* __restrict__ cstartM,
                                                int* __restrict__ cstartC,
                                                int* __restrict__ ccurM,
                                                int* __restrict__ ccurC) {
    __shared__ int wsum[4];
    const int t = threadIdx.x, lane = t & 63, wv = t >> 6;
    int s = 0;
    if (t < NBM)
        for (int b = 0; b < NSB; ++b) s += pmM[(long)b * NBM + t];
    int incl = wscan_incl(s, lane);
    if (lane == 63) wsum[wv] = incl;
    __syncthreads();
    int wadd = 0;
#pragma unroll
    for (int w = 0; w < 4; ++w) wadd += (w < wv) ? wsum[w] : 0;
    const int tot = incl + wadd;
    if (t < NBM) { cstartM[t] = tot - s; ccurM[t] = tot - s; }
    if (t == NBM - 1) cstartM[NBM] = tot;
    __syncthreads();
    int s2 = 0;
    if (t < NBC)
        for (int b = 0; b < NSB; ++b) s2 += pmC[(long)b * NBC + t];
    int incl2 = wscan_incl(s2, lane);
    if (lane == 63) wsum[wv] = incl2;
    __syncthreads();
    int wadd2 = 0;
#pragma unroll
    for (int w = 0; w < 4; ++w) wadd2 += (w < wv) ? wsum[w] : 0;
    const int tot2 = incl2 + wadd2;
    if (t < NBC) { cstartC[t] = tot2 - s2; ccurC[t] = tot2 - s2; }
    if (t == NBC - 1) cstartC[NBC] = tot2;
}

// ---------------- bucket sort pass 1: LDS-staged, block-aggregated cursors ----------
__global__ __launch_bounds__(256) void bsort2_k(const int* __restrict__ cm_src,
                                                const int* __restrict__ cm_dst,
                                                const int* __restrict__ mc_src,
                                                const int* __restrict__ mc_dst,
                                                int* __restrict__ ccurM,
                                                int* __restrict__ ccurC,
                                                int* __restrict__ bktM,
                                                int* __restrict__ bktC) {
    __shared__ int cnt[256], pfx[256], gbase[256];
    __shared__ int wsum[4];
    __shared__ int stage[CH];
    const int side = (blockIdx.x >= NSB);
    const int blk = blockIdx.x - side * NSB;
    const int* src = side ? mc_src : cm_src;
    const int* dst = side ? mc_dst : cm_dst;
    int* ccur = side ? ccurC : ccurM;
    int* bkt = side ? bktC : bktM;
    const int nb = side ? NBC : NBM;

    const int t = threadIdx.x, lane = t & 63, wv = t >> 6;
    const int e0 = blk * CH;
    const int n = min(CH, NE - e0);
    cnt[t] = 0;
    __syncthreads();
    for (int i = t; i < n; i += 256) atomicAdd(&cnt[dst[e0 + i] >> BSH], 1);
    __syncthreads();
    const int myc = (t < nb) ? cnt[t] : 0;
    int incl = wscan_incl(myc, lane);
    if (lane == 63) wsum[wv] = incl;
    __syncthreads();
    int wadd = 0;
#pragma unroll
    for (int w = 0; w < 4; ++w) wadd += (w < wv) ? wsum[w] : 0;
    const int excl = wadd + incl - myc;
    if (t < nb && myc > 0) gbase[t] = atomicAdd(&ccur[t], myc);
    pfx[t] = excl;
    cnt[t] = 0;
    __syncthreads();
    for (int i = t; i < n; i += 256) {
        const int d = dst[e0 + i];
        const int b = d >> BSH;
        const int p = pfx[b] + atomicAdd(&cnt[b], 1);
        stage[p] = (src[e0 + i] << BSH) | (d & (BW - 1));
    }
    __syncthreads();
    for (int b = wv; b < nb; b += 4) {
        const int c = cnt[b];
        if (c == 0) continue;
        const int gb = gbase[b], lo = pfx[b];
        for (int j = lane; j < c; j += 64) bkt[gb + j] = stage[lo + j];
    }
}

// ---------------- bucket sort pass 2 + fine-offset construction ----------------
__global__ __launch_bounds__(256) void bp22_k(const int* __restrict__ bktM,
                                              const int* __restrict__ cstartM,
                                              int* __restrict__ startM,
                                              int* __restrict__ srtM,
                                              const int* __restrict__ bktC,
                                              const int* __restrict__ cstartC,
                                              int* __restrict__ startC,
                                              int* __restrict__ srtC) {
    __shared__ int lcur[BW];
    __shared__ int wsum[4];
    const int side = (blockIdx.x >= NBM);
    const int blk = blockIdx.x - side * NBM;
    const int* bkt = side ? bktC : bktM;
    const int* cstart = side ? cstartC : cstartM;
    int* start = side ? startC : startM;
    int* srt = side ? srtC : srtM;
    const int n_nodes = side ? NC : NM;
    const int base = blk << BSH;
    const int t = threadIdx.x, lane = t & 63, wv = t >> 6;

    const int e0 = cstart[blk];
    const int e1 = cstart[blk + 1];

    for (int i = t; i < BW; i += 256) lcur[i] = 0;
    __syncthreads();
    for (int e = e0 + t; e < e1; e += 256) atomicAdd(&lcur[bkt[e] & (BW - 1)], 1);
    __syncthreads();

    const int c0 = lcur[4 * t + 0], c1 = lcur[4 * t + 1];
    const int c2 = lcur[4 * t + 2], c3 = lcur[4 * t + 3];
    const int local = c0 + c1 + c2 + c3;
    int incl = wscan_incl(local, lane);
    if (lane == 63) wsum[wv] = incl;
    __syncthreads();
    int wadd = 0;
#pragma unroll
    for (int w = 0; w < 4; ++w) wadd += (w < wv) ? wsum[w] : 0;
    const int p0 = e0 + wadd + incl - local;
    const int p1 = p0 + c0, p2 = p1 + c1, p3 = p2 + c2;
    lcur[4 * t + 0] = p0;
    lcur[4 * t + 1] = p1;
    lcur[4 * t + 2] = p2;
    lcur[4 * t + 3] = p3;
    if (base + 4 * t + 0 < n_nodes) start[base + 4 * t + 0] = p0;
    if (base + 4 * t + 1 < n_nodes) start[base + 4 * t + 1] = p1;
    if (base + 4 * t + 2 < n_nodes) start[base + 4 * t + 2] = p2;
    if (base + 4 * t + 3 < n_nodes) start[base + 4 * t + 3] = p3;
    if (t == 0 && base + BW >= n_nodes) start[n_nodes] = e1;
    __syncthreads();

    for (int e = e0 + t; e < e1; e += 256) {
        const int p = bkt[e];
        const int pos = atomicAdd(&lcur[p & (BW - 1)], 1);
        srt[pos] = p >> BSH;
    }
}

// ---------------- single-plane aggregation: 16-lane subgroup per node ----------------
__global__ __launch_bounds__(256) void agg16_k(const unsigned short* __restrict__ xhi,
                                               const int* __restrict__ start,
                                               const int* __restrict__ srt,
                                               unsigned short* __restrict__ mean16,
                                               int n_nodes) {
    const int sgid = (blockIdx.x * blockDim.x + threadIdx.x) >> 4;
    const int nsg = (gridDim.x * blockDim.x) >> 4;
    const int k4 = (threadIdx.x & 15) * 4;
    for (int n = sgid; n < n_nodes; n += nsg) {
        const int s0 = start[n], s1 = start[n + 1];
        f32x4 a0 = {0.f, 0.f, 0.f, 0.f}, a1 = {0.f, 0.f, 0.f, 0.f};
        f32x4 a2 = {0.f, 0.f, 0.f, 0.f}, a3 = {0.f, 0.f, 0.f, 0.f};
        int e = s0;
        for (; e + 3 < s1; e += 4) {
            const int i0 = srt[e + 0], i1 = srt[e + 1];
            const int i2 = srt[e + 2], i3 = srt[e + 3];
            const u16x4 v0 = *(const u16x4*)(xhi + (long)i0 * DF + k4);
            const u16x4 v1 = *(const u16x4*)(xhi + (long)i1 * DF + k4);
            const u16x4 v2 = *(const u16x4*)(xhi + (long)i2 * DF + k4);
            const u16x4 v3 = *(const u16x4*)(xhi + (long)i3 * DF + k4);
#pragma unroll
            for (int c = 0; c < 4; ++c) {
                a0[c] += bf16f((short)v0[c]);
                a1[c] += bf16f((short)v1[c]);
                a2[c] += bf16f((short)v2[c]);
                a3[c] += bf16f((short)v3[c]);
            }
        }
        for (; e < s1; ++e) {
            const int i0 = srt[e];
            const u16x4 v0 = *(const u16x4*)(xhi + (long)i0 * DF + k4);
#pragma unroll
            for (int c = 0; c < 4; ++c) a0[c] += bf16f((short)v0[c]);
        }
        const float inv = 1.0f / fmaxf((float)(s1 - s0), 1.0f);
        u16x4 o;
#pragma unroll
        for (int c = 0; c < 4; ++c)
            o[c] = (unsigned short)bf16rn(((a0[c] + a1[c]) + (a2[c] + a3[c])) * inv);
        *(u16x4*)(mean16 + (long)n * DF + k4) = o;
    }
}

#define MFMA(a, b, c) __builtin_amdgcn_mfma_f32_16x16x32_bf16((a), (b), (c), 0, 0, 0)

#define LOAD_W(Wl, Wr, col, g, wlh, wll, wrh, wrl)          \
    do {                                                    \
        _Pragma("unroll")                                   \
        for (int q = 0; q < 2; ++q) {                       \
            f32x4 tl0, tl1, tr0, tr1;                       \
            _Pragma("unroll")                               \
            for (int b = 0; b < 4; ++b) {                   \
                int k = 32 * q + 8 * (g) + b;               \
                tl0[b] = (Wl)[k * DF + (col)];              \
                tr0[b] = (Wr)[k * DF + (col)];              \
                tl1[b] = (Wl)[(k + 4) * DF + (col)];        \
                tr1[b] = (Wr)[(k + 4) * DF + (col)];        \
            }                                               \
            split8(tl0, tl1, wlh[q], wll[q]);               \
            split8(tr0, tr1, wrh[q], wrl[q]);               \
        }                                                   \
    } while (0)

// same but stride 16 (for composed 64x2-in-64x16 V matrices)
#define LOAD_W16(Wl, Wr, col, g, wlh, wll, wrh, wrl)        \
    do {                                                    \
        _Pragma("unroll")                                   \
        for (int q = 0; q < 2; ++q) {                       \
            f32x4 tl0, tl1, tr0, tr1;                       \
            _Pragma("unroll")                               \
            for (int b = 0; b < 4; ++b) {                   \
                int k = 32 * q + 8 * (g) + b;               \
                tl0[b] = (Wl)[k * 16 + (col)];              \
                tr0[b] = (Wr)[k * 16 + (col)];              \
                tl1[b] = (Wl)[(k + 4) * 16 + (col)];        \
                tr1[b] = (Wr)[(k + 4) * 16 + (col)];        \
            }                                               \
            split8(tl0, tl1, wlh[q], wll[q]);               \
            split8(tr0, tr1, wrh[q], wrl[q]);               \
        }                                                   \
    } while (0)

// ---------------- dense1 @ NM: hm16 = bf16(relu(mean16 @ Wl + xm16 @ Wr + b)) --------
__global__ __launch_bounds__(256) void dense1nm_k(const unsigned short* __restrict__ mean16,
                                                  const unsigned short* __restrict__ xm16,
                                                  const float* __restrict__ Wl,
                                                  const float* __restrict__ Wr,
                                                  const float* __restrict__ bias,
                                                  unsigned short* __restrict__ h16,
                                                  int n_nodes) {
    const int wglobal = (blockIdx.x * blockDim.x + threadIdx.x) >> 6;
    const int lane = threadIdx.x & 63;
    const int nwaves = (gridDim.x * blockDim.x) >> 6;
    const int ct = wglobal & 3;
    const int col = ct * 16 + (lane & 15);
    const int g = lane >> 4;

    bf16x8 wlh[2], wll[2], wrh[2], wrl[2];
    LOAD_W(Wl, Wr, col, g, wlh, wll, wrh, wrl);
    const float bv = bias[col];

    const int nrt = n_nodes >> 4;
    for (int rt = wglobal >> 2; rt < nrt; rt += nwaves >> 2) {
        const long rowA = (long)rt * 16 + (lane & 15);
        const bf16x8 m0 = *(const bf16x8*)(mean16 + rowA * DF + 8 * g);
        const bf16x8 m1 = *(const bf16x8*)(mean16 + rowA * DF + 32 + 8 * g);
        const bf16x8 x0 = *(const bf16x8*)(xm16 + rowA * DF + 8 * g);
        const bf16x8 x1 = *(const bf16x8*)(xm16 + rowA * DF + 32 + 8 * g);
        f32x4 acc = {0.f, 0.f, 0.f, 0.f};
        acc = MFMA(m0, wlh[0], acc);
        acc = MFMA(m0, wll[0], acc);
        acc = MFMA(m1, wlh[1], acc);
        acc = MFMA(m1, wll[1], acc);
        acc = MFMA(x0, wrh[0], acc);
        acc = MFMA(x0, wrl[0], acc);
        acc = MFMA(x1, wrh[1], acc);
        acc = MFMA(x1, wrl[1], acc);
#pragma unroll
        for (int r = 0; r < 4; ++r)
            h16[((long)rt * 16 + 4 * g + r) * DF + col] =
                (unsigned short)bf16rn(fmaxf(acc[r] + bv, 0.0f));
    }
}

// ---------------- fused customer kernel: gather means + layer1 + folded layer2 ------
// block = 64 nodes. 16 subgroups gather (xm,hm) means -> LDS; 4 waves do layer-1
// col-tiles; each wave does folded layer-2 (V = W2@Wlin) for its 16-node tile and
// stores out directly. No aggc2 kernel, no mean buffers, no shuffle-reduce.
__global__ __launch_bounds__(256) void densec_k(const unsigned short* __restrict__ xp,
                                                const unsigned short* __restrict__ hp,
                                                const int* __restrict__ start,
                                                const int* __restrict__ srt,
                                                const unsigned short* __restrict__ xc,
                                                const float* __restrict__ Wl1,
                                                const float* __restrict__ Wr1,
                                                const float* __restrict__ b1,
                                                const float* __restrict__ Vl,
                                                const float* __restrict__ Vr,
                                                const float* __restrict__ bo,
                                                float* __restrict__ out) {
    __shared__ unsigned short sMX[64][72];
    __shared__ unsigned short sMH[64][72];
    __shared__ unsigned short sH[64][72];
    const int t = threadIdx.x;
    const int lane = t & 63;
    const int wv = t >> 6;
    const int col = wv * 16 + (lane & 15);
    const int g = lane >> 4;

    bf16x8 w1lh[2], w1ll[2], w1rh[2], w1rl[2];
    LOAD_W(Wl1, Wr1, col, g, w1lh, w1ll, w1rh, w1rl);
    const float bv1 = b1[col];
    bf16x8 vlh[2], vll[2], vrh[2], vrl[2];
    LOAD_W16(Vl, Vr, (lane & 15), g, vlh, vll, vrh, vrl);
    const float bo2 = ((lane & 15) < 2) ? bo[lane & 15] : 0.0f;

    const int base = blockIdx.x * 64;

    // ---- gather phase: subgroup sg handles nodes base + sg + 16r ----
    const int sg = t >> 4;
    const int k4 = (lane & 15) * 4;
#pragma unroll
    for (int r = 0; r < 4; ++r) {
        const int nl = r * 16 + sg;
        const int n = base + nl;
        const int s0 = start[n], s1 = start[n + 1];
        f32x4 ax0 = {0.f, 0.f, 0.f, 0.f}, ah0 = {0.f, 0.f, 0.f, 0.f};
        f32x4 ax1 = {0.f, 0.f, 0.f, 0.f}, ah1 = {0.f, 0.f, 0.f, 0.f};
        int e = s0;
        for (; e + 1 < s1; e += 2) {
            const int iA = srt[e], iB = srt[e + 1];
            const u16x4 vxA = *(const u16x4*)(xp + (long)iA * DF + k4);
            const u16x4 vhA = *(const u16x4*)(hp + (long)iA * DF + k4);
            const u16x4 vxB = *(const u16x4*)(xp + (long)iB * DF + k4);
            const u16x4 vhB = *(const u16x4*)(hp + (long)iB * DF + k4);
#pragma unroll
            for (int c = 0; c < 4; ++c) {
                ax0[c] += bf16f((short)vxA[c]);
                ah0[c] += bf16f((short)vhA[c]);
                ax1[c] += bf16f((short)vxB[c]);
                ah1[c] += bf16f((short)vhB[c]);
            }
        }
        if (e < s1) {
            const int iA = srt[e];
            const u16x4 vxA = *(const u16x4*)(xp + (long)iA * DF + k4);
            const u16x4 vhA = *(const u16x4*)(hp + (long)iA * DF + k4);
#pragma unroll
            for (int c = 0; c < 4; ++c) {
                ax0[c] += bf16f((short)vxA[c]);
                ah0[c] += bf16f((short)vhA[c]);
            }
        }
        const float inv = 1.0f / fmaxf((float)(s1 - s0), 1.0f);
        u16x4 ox, oh;
#pragma unroll
        for (int c = 0; c < 4; ++c) {
            ox[c] = (unsigned short)bf16rn((ax0[c] + ax1[c]) * inv);
            oh[c] = (unsigned short)bf16rn((ah0[c] + ah1[c]) * inv);
        }
        *(u16x4*)&sMX[nl][k4] = ox;
        *(u16x4*)&sMH[nl][k4] = oh;
    }
    __syncthreads();

    // ---- layer 1: wave wv computes col-tile wv for all 4 row-tiles ----
#pragma unroll
    for (int tt = 0; tt < 4; ++tt) {
        const int ar = tt * 16 + (lane & 15);
        const bf16x8 mx0 = *(const bf16x8*)&sMX[ar][8 * g];
        const bf16x8 mx1 = *(const bf16x8*)&sMX[ar][32 + 8 * g];
        const long grow = (long)(base + ar);
        const bf16x8 x0 = *(const bf16x8*)(xc + grow * DF + 8 * g);
        const bf16x8 x1 = *(const bf16x8*)(xc + grow * DF + 32 + 8 * g);
        f32x4 acc = {0.f, 0.f, 0.f, 0.f};
        acc = MFMA(mx0, w1lh[0], acc);
        acc = MFMA(mx0, w1ll[0], acc);
        acc = MFMA(mx1, w1lh[1], acc);
        acc = MFMA(mx1, w1ll[1], acc);
        acc = MFMA(x0, w1rh[0], acc);
        acc = MFMA(x0, w1rl[0], acc);
        acc = MFMA(x1, w1rh[1], acc);
        acc = MFMA(x1, w1rl[1], acc);
#pragma unroll
        for (int r = 0; r < 4; ++r)
            sH[tt * 16 + 4 * g + r][col] = (unsigned short)bf16rn(fmaxf(acc[r] + bv1, 0.0f));
    }
    __syncthreads();

    // ---- folded layer 2: wave wv owns row-tile wv; out = mh@Vl + hc@Vr + bo ----
    const int ar2 = wv * 16 + (lane & 15);
    const bf16x8 mh0 = *(const bf16x8*)&sMH[ar2][8 * g];
    const bf16x8 mh1 = *(const bf16x8*)&sMH[ar2][32 + 8 * g];
    const bf16x8 hc0 = *(const bf16x8*)&sH[ar2][8 * g];
    const bf16x8 hc1 = *(const bf16x8*)&sH[ar2][32 + 8 * g];
    f32x4 a2 = {0.f, 0.f, 0.f, 0.f};
    a2 = MFMA(mh0, vlh[0], a2);
    a2 = MFMA(mh0, vll[0], a2);
    a2 = MFMA(mh1, vlh[1], a2);
    a2 = MFMA(mh1, vll[1], a2);
    a2 = MFMA(hc0, vrh[0], a2);
    a2 = MFMA(hc0, vrl[0], a2);
    a2 = MFMA(hc1, vrh[1], a2);
    a2 = MFMA(hc1, vrl[1], a2);
    if ((lane & 15) < 2) {
#pragma unroll
        for (int r = 0; r < 4; ++r) {
            const long node = (long)base + wv * 16 + 4 * g + r;
            out[node * 2 + (lane & 15)] = a2[r] + bo2;
        }
    }
}

extern "C" void kernel_launch(void* const* d_in, const int* in_sizes, int n_in,
                              void* d_out, int out_size, void* d_ws, size_t ws_size,
                              hipStream_t stream) {
    const float* x_c = (const float*)d_in[0];
    const float* x_m = (const float*)d_in[1];
    const int* cm_src = (const int*)d_in[2];
    const int* cm_dst = (const int*)d_in[3];
    const int* mc_src = (const int*)d_in[4];
    const int* mc_dst = (const int*)d_in[5];
    const float* Wl1_cm = (const float*)d_in[6];
    const float* Wr1_cm = (const float*)d_in[7];
    const float* b1_cm = (const float*)d_in[8];
    const float* Wl1_mc = (const float*)d_in[9];
    const float* Wr1_mc = (const float*)d_in[10];
    const float* b1_mc = (const float*)d_in[11];
    // layer-2 cm weights (d_in[12..14]) are dead: h2_m is unused in the reference
    const float* Wl2_mc = (const float*)d_in[15];
    const float* Wr2_mc = (const float*)d_in[16];
    const float* b2_mc = (const float*)d_in[17];
    const float* W_lin = (const float*)d_in[18];
    const float* b_lin = (const float*)d_in[19];
    float* out = (float*)d_out;

    // ---- workspace layout (~70 MB) ----
    unsigned short* up = (unsigned short*)d_ws;
    unsigned short* aggm16 = up;                        // NM*64
    unsigned short* hm16 = aggm16 + (long)NM * DF;      // NM*64
    unsigned short* xm16 = hm16 + (long)NM * DF;        // NM*64
    unsigned short* xc16 = xm16 + (long)NM * DF;        // NC*64
    float* Vl = (float*)(xc16 + (long)NC * DF);         // 64*16
    float* Vr = Vl + 64 * 16;                           // 64*16
    float* bo = Vr + 64 * 16;                           // 2 (+pad)
    int* ip = (int*)(bo + 4);

    int* startM = ip;                   // NM+1 (written by bp22)
    int* startC = startM + (NM + 1);    // NC+1 (written by bp22)
    int* cstartM = startC + (NC + 1);   // NBM+1
    int* cstartC = cstartM + (NBM + 1); // NBC+1
    int* ccurM = cstartC + (NBC + 1);   // NBM
    int* ccurC = ccurM + NBM;           // NBC
    int* pmM = ccurC + NBC;             // NSB*NBM
    int* pmC = pmM + NSB * NBM;         // NSB*NBC
    int* srt_cm = pmC + NSB * NBC;      // NE
    int* srt_mc = srt_cm + NE;          // NE
    int* bktM = srt_mc + NE;            // NE
    int* bktC = bktM + NE;              // NE

    // coarse hist + presplit + V-compose -> coarse scan -> sort -> fine offsets
    prep_k<<<2 * NSB + PSB + 1, 256, 0, stream>>>(cm_dst, mc_dst, pmM, pmC,
                                                  x_c, x_m, (u16x4*)xc16, (u16x4*)xm16,
                                                  Wl2_mc, Wr2_mc, b2_mc, W_lin, b_lin,
                                                  Vl, Vr, bo);
    cscan2_k<<<1, 256, 0, stream>>>(pmM, pmC, cstartM, cstartC, ccurM, ccurC);
    bsort2_k<<<2 * NSB, 256, 0, stream>>>(cm_src, cm_dst, mc_src, mc_dst,
                                          ccurM, ccurC, bktM, bktC);
    bp22_k<<<NBM + NBC, 256, 0, stream>>>(bktM, cstartM, startM, srt_cm,
                                          bktC, cstartC, startC, srt_mc);

    // layer 1 @ merchants: m-mean (bf16) then dense -> hm16
    agg16_k<<<NM / 16, 256, 0, stream>>>(xc16, startM, srt_cm, aggm16, NM);
    dense1nm_k<<<1024, 256, 0, stream>>>(aggm16, xm16, Wl1_cm, Wr1_cm, b1_cm, hm16, NM);

    // customers: fully fused gather + layer1 + folded layer2 (+W_lin) -> out
    densec_k<<<NC / 64, 256, 0, stream>>>(xm16, hm16, startC, srt_mc, xc16,
                                          Wl1_mc, Wr1_mc, b1_mc,
                                          Vl, Vr, bo, out);
}

// Round 16
// 257.649 us; speedup vs baseline: 1.1526x; 1.1526x over previous
//
#include <hip/hip_runtime.h>

#define NC 200000
#define NM 50000
#define NE 1000000
#define DF 64   // feature dim (D == H == 64)

#define BSH 10
#define BW 1024
#define NBM ((NM + BW - 1) >> BSH)   // 49
#define NBC ((NC + BW - 1) >> BSH)   // 196
#define CH 4096                      // edges per chunk block
#define NSB ((NE + CH - 1) / CH)     // 245
#define PSB 1024                     // presplit blocks inside prep_k

typedef __attribute__((ext_vector_type(8))) short bf16x8;
typedef __attribute__((ext_vector_type(4))) float f32x4;
typedef __attribute__((ext_vector_type(4))) unsigned short u16x4;

// ---------------- round-to-nearest bf16 helpers ----------------
__device__ __forceinline__ short bf16rn(float x) {
    unsigned u = __builtin_bit_cast(unsigned, x);
    unsigned r = u + 0x7FFFu + ((u >> 16) & 1u);
    return (short)(r >> 16);
}
__device__ __forceinline__ float bf16f(short h) {
    unsigned u = ((unsigned)(unsigned short)h) << 16;
    return __builtin_bit_cast(float, u);
}
__device__ __forceinline__ void split8(const f32x4 u, const f32x4 v,
                                       bf16x8& hi, bf16x8& lo) {
#pragma unroll
    for (int b = 0; b < 4; ++b) {
        short h = bf16rn(u[b]);
        hi[b] = h;
        lo[b] = bf16rn(u[b] - bf16f(h));
    }
#pragma unroll
    for (int b = 0; b < 4; ++b) {
        short h = bf16rn(v[b]);
        hi[4 + b] = h;
        lo[4 + b] = bf16rn(v[b] - bf16f(h));
    }
}

// ---------------- wave-wide inclusive scan (64 lanes, no barriers) ----------------
__device__ __forceinline__ int wscan_incl(int v, int lane) {
#pragma unroll
    for (int off = 1; off < 64; off <<= 1) {
        int y = __shfl_up(v, off);
        if (lane >= off) v += y;
    }
    return v;
}

// ---- prep: coarse hists (no global atomics) + bf16 presplit + W_lin folding ------
__global__ __launch_bounds__(256) void prep_k(const int* __restrict__ cm_dst,
                                              const int* __restrict__ mc_dst,
                                              int* __restrict__ pmM,
                                              int* __restrict__ pmC,
                                              const float* __restrict__ x_c,
                                              const float* __restrict__ x_m,
                                              u16x4* __restrict__ xc16,
                                              u16x4* __restrict__ xm16,
                                              const float* __restrict__ Wl2,
                                              const float* __restrict__ Wr2,
                                              const float* __restrict__ b2,
                                              const float* __restrict__ Wlin,
                                              const float* __restrict__ blin,
                                              float* __restrict__ Vl,
                                              float* __restrict__ Vr,
                                              float* __restrict__ bo) {
    __shared__ int cnt[256];
    const int t = threadIdx.x;
    if (blockIdx.x < 2 * NSB) {
        const int side = (blockIdx.x >= NSB);
        const int blk = blockIdx.x - side * NSB;
        const int* dst = side ? mc_dst : cm_dst;
        int* pm = side ? pmC : pmM;
        const int nb = side ? NBC : NBM;
        cnt[t] = 0;
        __syncthreads();
        const int e0 = blk * CH;
        const int n = min(CH, NE - e0);
        for (int i = t; i < n; i += 256) atomicAdd(&cnt[dst[e0 + i] >> BSH], 1);
        __syncthreads();
        if (t < nb) pm[(long)blk * nb + t] = cnt[t];
    } else if (blockIdx.x < 2 * NSB + PSB) {
        const int blk = blockIdx.x - 2 * NSB;
        const int NC4 = NC * (DF / 4);
        const int NT4 = (NC + NM) * (DF / 4);
        const int st = PSB * 256;
        for (int i = blk * 256 + t; i < NT4; i += st) {
            const bool isc = (i < NC4);
            const int j = isc ? i : i - NC4;
            const f32x4 v = isc ? ((const f32x4*)x_c)[j] : ((const f32x4*)x_m)[j];
            u16x4 o;
#pragma unroll
            for (int b = 0; b < 4; ++b) o[b] = (unsigned short)bf16rn(v[b]);
            if (isc) xc16[j] = o;
            else     xm16[j] = o;
        }
    } else {
        // compose Vl = Wl2@Wlin, Vr = Wr2@Wlin (64x2 padded to 64x16), bo = b2@Wlin+blin
        for (int i = t; i < 2 * 64 * 16; i += 256) {
            float* dst = (i < 1024) ? Vl : Vr;
            dst[i & 1023] = 0.0f;
        }
        __syncthreads();
        if (t < 128) {
            const int k = t >> 1, o = t & 1;
            float sl = 0.f, sr = 0.f;
            for (int j = 0; j < 64; ++j) {
                sl += Wl2[k * 64 + j] * Wlin[j * 2 + o];
                sr += Wr2[k * 64 + j] * Wlin[j * 2 + o];
            }
            Vl[k * 16 + o] = sl;
            Vr[k * 16 + o] = sr;
        }
        if (t < 2) {
            float s = blin[t];
            for (int j = 0; j < 64; ++j) s += b2[j] * Wlin[j * 2 + t];
            bo[t] = s;
        }
    }
}

// ---------------- coarse reduce+scan (one tiny block): cstart + ccur init ----------
__global__ __launch_bounds__(256) void cscan2_k(const int* __restrict__ pmM,
                                                const int* __restrict__ pmC,
                                                int* __restrict__ cstartM,
                                                int* __restrict__ cstartC,
                                                int* __restrict__ ccurM,
                                                int* __restrict__ ccurC) {
    __shared__ int wsum[4];
    const int t = threadIdx.x, lane = t & 63, wv = t >> 6;
    int s = 0;
    if (t < NBM)
        for (int b = 0; b < NSB; ++b) s += pmM[(long)b * NBM + t];
    int incl = wscan_incl(s, lane);
    if (lane == 63) wsum[wv] = incl;
    __syncthreads();
    int wadd = 0;
#pragma unroll
    for (int w = 0; w < 4; ++w) wadd += (w < wv) ? wsum[w] : 0;
    const int tot = incl + wadd;
    if (t < NBM) { cstartM[t] = tot - s; ccurM[t] = tot - s; }
    if (t == NBM - 1) cstartM[NBM] = tot;
    __syncthreads();
    int s2 = 0;
    if (t < NBC)
        for (int b = 0; b < NSB; ++b) s2 += pmC[(long)b * NBC + t];
    int incl2 = wscan_incl(s2, lane);
    if (lane == 63) wsum[wv] = incl2;
    __syncthreads();
    int wadd2 = 0;
#pragma unroll
    for (int w = 0; w < 4; ++w) wadd2 += (w < wv) ? wsum[w] : 0;
    const int tot2 = incl2 + wadd2;
    if (t < NBC) { cstartC[t] = tot2 - s2; ccurC[t] = tot2 - s2; }
    if (t == NBC - 1) cstartC[NBC] = tot2;
}

// ---------------- bucket sort pass 1: LDS-staged, block-aggregated cursors ----------
__global__ __launch_bounds__(256) void bsort2_k(const int* __restrict__ cm_src,
                                                const int* __restrict__ cm_dst,
                                                const int* __restrict__ mc_src,
                                                const int* __restrict__ mc_dst,
                                                int* __restrict__ ccurM,
                                                int* __restrict__ ccurC,
                                                int* __restrict__ bktM,
                                                int* __restrict__ bktC) {
    __shared__ int cnt[256], pfx[256], gbase[256];
    __shared__ int wsum[4];
    __shared__ int stage[CH];
    const int side = (blockIdx.x >= NSB);
    const int blk = blockIdx.x - side * NSB;
    const int* src = side ? mc_src : cm_src;
    const int* dst = side ? mc_dst : cm_dst;
    int* ccur = side ? ccurC : ccurM;
    int* bkt = side ? bktC : bktM;
    const int nb = side ? NBC : NBM;

    const int t = threadIdx.x, lane = t & 63, wv = t >> 6;
    const int e0 = blk * CH;
    const int n = min(CH, NE - e0);
    cnt[t] = 0;
    __syncthreads();
    for (int i = t; i < n; i += 256) atomicAdd(&cnt[dst[e0 + i] >> BSH], 1);
    __syncthreads();
    const int myc = (t < nb) ? cnt[t] : 0;
    int incl = wscan_incl(myc, lane);
    if (lane == 63) wsum[wv] = incl;
    __syncthreads();
    int wadd = 0;
#pragma unroll
    for (int w = 0; w < 4; ++w) wadd += (w < wv) ? wsum[w] : 0;
    const int excl = wadd + incl - myc;
    if (t < nb && myc > 0) gbase[t] = atomicAdd(&ccur[t], myc);
    pfx[t] = excl;
    cnt[t] = 0;
    __syncthreads();
    for (int i = t; i < n; i += 256) {
        const int d = dst[e0 + i];
        const int b = d >> BSH;
        const int p = pfx[b] + atomicAdd(&cnt[b], 1);
        stage[p] = (src[e0 + i] << BSH) | (d & (BW - 1));
    }
    __syncthreads();
    for (int b = wv; b < nb; b += 4) {
        const int c = cnt[b];
        if (c == 0) continue;
        const int gb = gbase[b], lo = pfx[b];
        for (int j = lane; j < c; j += 64) bkt[gb + j] = stage[lo + j];
    }
}

// ---------------- bucket sort pass 2 + fine-offset construction ----------------
__global__ __launch_bounds__(256) void bp22_k(const int* __restrict__ bktM,
                                              const int* __restrict__ cstartM,
                                              int* __restrict__ startM,
                                              int* __restrict__ srtM,
                                              const int* __restrict__ bktC,
                                              const int* __restrict__ cstartC,
                                              int* __restrict__ startC,
                                              int* __restrict__ srtC) {
    __shared__ int lcur[BW];
    __shared__ int wsum[4];
    const int side = (blockIdx.x >= NBM);
    const int blk = blockIdx.x - side * NBM;
    const int* bkt = side ? bktC : bktM;
    const int* cstart = side ? cstartC : cstartM;
    int* start = side ? startC : startM;
    int* srt = side ? srtC : srtM;
    const int n_nodes = side ? NC : NM;
    const int base = blk << BSH;
    const int t = threadIdx.x, lane = t & 63, wv = t >> 6;

    const int e0 = cstart[blk];
    const int e1 = cstart[blk + 1];

    for (int i = t; i < BW; i += 256) lcur[i] = 0;
    __syncthreads();
    for (int e = e0 + t; e < e1; e += 256) atomicAdd(&lcur[bkt[e] & (BW - 1)], 1);
    __syncthreads();

    const int c0 = lcur[4 * t + 0], c1 = lcur[4 * t + 1];
    const int c2 = lcur[4 * t + 2], c3 = lcur[4 * t + 3];
    const int local = c0 + c1 + c2 + c3;
    int incl = wscan_incl(local, lane);
    if (lane == 63) wsum[wv] = incl;
    __syncthreads();
    int wadd = 0;
#pragma unroll
    for (int w = 0; w < 4; ++w) wadd += (w < wv) ? wsum[w] : 0;
    const int p0 = e0 + wadd + incl - local;
    const int p1 = p0 + c0, p2 = p1 + c1, p3 = p2 + c2;
    lcur[4 * t + 0] = p0;
    lcur[4 * t + 1] = p1;
    lcur[4 * t + 2] = p2;
    lcur[4 * t + 3] = p3;
    if (base + 4 * t + 0 < n_nodes) start[base + 4 * t + 0] = p0;
    if (base + 4 * t + 1 < n_nodes) start[base + 4 * t + 1] = p1;
    if (base + 4 * t + 2 < n_nodes) start[base + 4 * t + 2] = p2;
    if (base + 4 * t + 3 < n_nodes) start[base + 4 * t + 3] = p3;
    if (t == 0 && base + BW >= n_nodes) start[n_nodes] = e1;
    __syncthreads();

    for (int e = e0 + t; e < e1; e += 256) {
        const int p = bkt[e];
        const int pos = atomicAdd(&lcur[p & (BW - 1)], 1);
        srt[pos] = p >> BSH;
    }
}

// ---------------- single-plane aggregation: 16-lane subgroup per node ----------------
__global__ __launch_bounds__(256) void agg16_k(const unsigned short* __restrict__ xhi,
                                               const int* __restrict__ start,
                                               const int* __restrict__ srt,
                                               unsigned short* __restrict__ mean16,
                                               int n_nodes) {
    const int sgid = (blockIdx.x * blockDim.x + threadIdx.x) >> 4;
    const int nsg = (gridDim.x * blockDim.x) >> 4;
    const int k4 = (threadIdx.x & 15) * 4;
    for (int n = sgid; n < n_nodes; n += nsg) {
        const int s0 = start[n], s1 = start[n + 1];
        f32x4 a0 = {0.f, 0.f, 0.f, 0.f}, a1 = {0.f, 0.f, 0.f, 0.f};
        f32x4 a2 = {0.f, 0.f, 0.f, 0.f}, a3 = {0.f, 0.f, 0.f, 0.f};
        int e = s0;
        for (; e + 3 < s1; e += 4) {
            const int i0 = srt[e + 0], i1 = srt[e + 1];
            const int i2 = srt[e + 2], i3 = srt[e + 3];
            const u16x4 v0 = *(const u16x4*)(xhi + (long)i0 * DF + k4);
            const u16x4 v1 = *(const u16x4*)(xhi + (long)i1 * DF + k4);
            const u16x4 v2 = *(const u16x4*)(xhi + (long)i2 * DF + k4);
            const u16x4 v3 = *(const u16x4*)(xhi + (long)i3 * DF + k4);
#pragma unroll
            for (int c = 0; c < 4; ++c) {
                a0[c] += bf16f((short)v0[c]);
                a1[c] += bf16f((short)v1[c]);
                a2[c] += bf16f((short)v2[c]);
                a3[c] += bf16f((short)v3[c]);
            }
        }
        for (; e < s1; ++e) {
            const int i0 = srt[e];
            const u16x4 v0 = *(const u16x4*)(xhi + (long)i0 * DF + k4);
#pragma unroll
            for (int c = 0; c < 4; ++c) a0[c] += bf16f((short)v0[c]);
        }
        const float inv = 1.0f / fmaxf((float)(s1 - s0), 1.0f);
        u16x4 o;
#pragma unroll
        for (int c = 0; c < 4; ++c)
            o[c] = (unsigned short)bf16rn(((a0[c] + a1[c]) + (a2[c] + a3[c])) * inv);
        *(u16x4*)(mean16 + (long)n * DF + k4) = o;
    }
}

// ---------------- dual-plane aggregation: 16-lane subgroup per node ----------------
__global__ __launch_bounds__(256) void aggc2_k(const unsigned short* __restrict__ xp,
                                               const unsigned short* __restrict__ hp,
                                               const int* __restrict__ start,
                                               const int* __restrict__ srt,
                                               unsigned short* __restrict__ mx,
                                               unsigned short* __restrict__ mh, int n_nodes) {
    const int sgid = (blockIdx.x * blockDim.x + threadIdx.x) >> 4;
    const int nsg = (gridDim.x * blockDim.x) >> 4;
    const int k4 = (threadIdx.x & 15) * 4;
    for (int n = sgid; n < n_nodes; n += nsg) {
        const int s0 = start[n], s1 = start[n + 1];
        f32x4 ax0 = {0.f, 0.f, 0.f, 0.f}, ah0 = {0.f, 0.f, 0.f, 0.f};
        f32x4 ax1 = {0.f, 0.f, 0.f, 0.f}, ah1 = {0.f, 0.f, 0.f, 0.f};
        int e = s0;
        for (; e + 1 < s1; e += 2) {
            const int iA = srt[e], iB = srt[e + 1];
            const u16x4 vxA = *(const u16x4*)(xp + (long)iA * DF + k4);
            const u16x4 vhA = *(const u16x4*)(hp + (long)iA * DF + k4);
            const u16x4 vxB = *(const u16x4*)(xp + (long)iB * DF + k4);
            const u16x4 vhB = *(const u16x4*)(hp + (long)iB * DF + k4);
#pragma unroll
            for (int c = 0; c < 4; ++c) {
                ax0[c] += bf16f((short)vxA[c]);
                ah0[c] += bf16f((short)vhA[c]);
                ax1[c] += bf16f((short)vxB[c]);
                ah1[c] += bf16f((short)vhB[c]);
            }
        }
        if (e < s1) {
            const int iA = srt[e];
            const u16x4 vxA = *(const u16x4*)(xp + (long)iA * DF + k4);
            const u16x4 vhA = *(const u16x4*)(hp + (long)iA * DF + k4);
#pragma unroll
            for (int c = 0; c < 4; ++c) {
                ax0[c] += bf16f((short)vxA[c]);
                ah0[c] += bf16f((short)vhA[c]);
            }
        }
        const float inv = 1.0f / fmaxf((float)(s1 - s0), 1.0f);
        u16x4 ox, oh;
#pragma unroll
        for (int c = 0; c < 4; ++c) {
            ox[c] = (unsigned short)bf16rn((ax0[c] + ax1[c]) * inv);
            oh[c] = (unsigned short)bf16rn((ah0[c] + ah1[c]) * inv);
        }
        *(u16x4*)(mx + (long)n * DF + k4) = ox;
        *(u16x4*)(mh + (long)n * DF + k4) = oh;
    }
}

#define MFMA(a, b, c) __builtin_amdgcn_mfma_f32_16x16x32_bf16((a), (b), (c), 0, 0, 0)

#define LOAD_W(Wl, Wr, col, g, wlh, wll, wrh, wrl)          \
    do {                                                    \
        _Pragma("unroll")                                   \
        for (int q = 0; q < 2; ++q) {                       \
            f32x4 tl0, tl1, tr0, tr1;                       \
            _Pragma("unroll")                               \
            for (int b = 0; b < 4; ++b) {                   \
                int k = 32 * q + 8 * (g) + b;               \
                tl0[b] = (Wl)[k * DF + (col)];              \
                tr0[b] = (Wr)[k * DF + (col)];              \
                tl1[b] = (Wl)[(k + 4) * DF + (col)];        \
                tr1[b] = (Wr)[(k + 4) * DF + (col)];        \
            }                                               \
            split8(tl0, tl1, wlh[q], wll[q]);               \
            split8(tr0, tr1, wrh[q], wrl[q]);               \
        }                                                   \
    } while (0)

// same but stride 16 (for composed 64x2-in-64x16 V matrices)
#define LOAD_W16(Wl, Wr, col, g, wlh, wll, wrh, wrl)        \
    do {                                                    \
        _Pragma("unroll")                                   \
        for (int q = 0; q < 2; ++q) {                       \
            f32x4 tl0, tl1, tr0, tr1;                       \
            _Pragma("unroll")                               \
            for (int b = 0; b < 4; ++b) {                   \
                int k = 32 * q + 8 * (g) + b;               \
                tl0[b] = (Wl)[k * 16 + (col)];              \
                tr0[b] = (Wr)[k * 16 + (col)];              \
                tl1[b] = (Wl)[(k + 4) * 16 + (col)];        \
                tr1[b] = (Wr)[(k + 4) * 16 + (col)];        \
            }                                               \
            split8(tl0, tl1, wlh[q], wll[q]);               \
            split8(tr0, tr1, wrh[q], wrl[q]);               \
        }                                                   \
    } while (0)

// ---------------- dense1 @ NM: hm16 = bf16(relu(mean16 @ Wl + xm16 @ Wr + b)) --------
__global__ __launch_bounds__(256) void dense1nm_k(const unsigned short* __restrict__ mean16,
                                                  const unsigned short* __restrict__ xm16,
                                                  const float* __restrict__ Wl,
                                                  const float* __restrict__ Wr,
                                                  const float* __restrict__ bias,
                                                  unsigned short* __restrict__ h16,
                                                  int n_nodes) {
    const int wglobal = (blockIdx.x * blockDim.x + threadIdx.x) >> 6;
    const int lane = threadIdx.x & 63;
    const int nwaves = (gridDim.x * blockDim.x) >> 6;
    const int ct = wglobal & 3;
    const int col = ct * 16 + (lane & 15);
    const int g = lane >> 4;

    bf16x8 wlh[2], wll[2], wrh[2], wrl[2];
    LOAD_W(Wl, Wr, col, g, wlh, wll, wrh, wrl);
    const float bv = bias[col];

    const int nrt = n_nodes >> 4;
    for (int rt = wglobal >> 2; rt < nrt; rt += nwaves >> 2) {
        const long rowA = (long)rt * 16 + (lane & 15);
        const bf16x8 m0 = *(const bf16x8*)(mean16 + rowA * DF + 8 * g);
        const bf16x8 m1 = *(const bf16x8*)(mean16 + rowA * DF + 32 + 8 * g);
        const bf16x8 x0 = *(const bf16x8*)(xm16 + rowA * DF + 8 * g);
        const bf16x8 x1 = *(const bf16x8*)(xm16 + rowA * DF + 32 + 8 * g);
        f32x4 acc = {0.f, 0.f, 0.f, 0.f};
        acc = MFMA(m0, wlh[0], acc);
        acc = MFMA(m0, wll[0], acc);
        acc = MFMA(m1, wlh[1], acc);
        acc = MFMA(m1, wll[1], acc);
        acc = MFMA(x0, wrh[0], acc);
        acc = MFMA(x0, wrl[0], acc);
        acc = MFMA(x1, wrh[1], acc);
        acc = MFMA(x1, wrl[1], acc);
#pragma unroll
        for (int r = 0; r < 4; ++r)
            h16[((long)rt * 16 + 4 * g + r) * DF + col] =
                (unsigned short)bf16rn(fmaxf(acc[r] + bv, 0.0f));
    }
}

// ---------------- customer dense (split): layer1 + folded layer2, direct store ------
// V = W2@Wlin folded -> no shuffle epilogue, no sOut; parity sH -> 1 barrier/tile.
__global__ __launch_bounds__(256) void densec_k(const unsigned short* __restrict__ meanx,
                                                const unsigned short* __restrict__ meanh,
                                                const unsigned short* __restrict__ xc,
                                                const float* __restrict__ Wl1,
                                                const float* __restrict__ Wr1,
                                                const float* __restrict__ b1,
                                                const float* __restrict__ Vl,
                                                const float* __restrict__ Vr,
                                                const float* __restrict__ bo,
                                                float* __restrict__ out, int n_nodes) {
    __shared__ unsigned short sH[2][16][72];
    const int t = threadIdx.x;
    const int lane = t & 63;
    const int wv = t >> 6;
    const int col = wv * 16 + (lane & 15);
    const int g = lane >> 4;

    bf16x8 w1lh[2], w1ll[2], w1rh[2], w1rl[2];
    LOAD_W(Wl1, Wr1, col, g, w1lh, w1ll, w1rh, w1rl);
    const float bv1 = b1[col];
    bf16x8 vlh[2], vll[2], vrh[2], vrl[2];
    LOAD_W16(Vl, Vr, (lane & 15), g, vlh, vll, vrh, vrl);
    const float bo2 = ((lane & 15) < 2) ? bo[lane & 15] : 0.0f;

    const int nrt = n_nodes >> 4;
    int par = 0;
    for (int rt = blockIdx.x; rt < nrt; rt += gridDim.x, par ^= 1) {
        const long rowA = (long)rt * 16 + (lane & 15);
        const bf16x8 mx0 = *(const bf16x8*)(meanx + rowA * DF + 8 * g);
        const bf16x8 mx1 = *(const bf16x8*)(meanx + rowA * DF + 32 + 8 * g);
        const bf16x8 mh0 = *(const bf16x8*)(meanh + rowA * DF + 8 * g);
        const bf16x8 mh1 = *(const bf16x8*)(meanh + rowA * DF + 32 + 8 * g);
        const bf16x8 xc0 = *(const bf16x8*)(xc + rowA * DF + 8 * g);
        const bf16x8 xc1 = *(const bf16x8*)(xc + rowA * DF + 32 + 8 * g);

        // ---- layer 1: h_c = relu(meanx @ Wl1 + x_c @ Wr1 + b1) ----
        f32x4 acc = {0.f, 0.f, 0.f, 0.f};
        acc = MFMA(mx0, w1lh[0], acc);
        acc = MFMA(mx0, w1ll[0], acc);
        acc = MFMA(mx1, w1lh[1], acc);
        acc = MFMA(mx1, w1ll[1], acc);
        acc = MFMA(xc0, w1rh[0], acc);
        acc = MFMA(xc0, w1rl[0], acc);
        acc = MFMA(xc1, w1rh[1], acc);
        acc = MFMA(xc1, w1rl[1], acc);
#pragma unroll
        for (int r = 0; r < 4; ++r)
            sH[par][4 * g + r][col] = (unsigned short)bf16rn(fmaxf(acc[r] + bv1, 0.0f));
        __syncthreads();

        // ---- folded layer 2: out = meanh @ Vl + h_c @ Vr + bo (cols 0,1 real) ----
        const bf16x8 hc0 = *(const bf16x8*)&sH[par][lane & 15][8 * g];
        const bf16x8 hc1 = *(const bf16x8*)&sH[par][lane & 15][32 + 8 * g];
        f32x4 a2 = {0.f, 0.f, 0.f, 0.f};
        a2 = MFMA(mh0, vlh[0], a2);
        a2 = MFMA(mh0, vll[0], a2);
        a2 = MFMA(mh1, vlh[1], a2);
        a2 = MFMA(mh1, vll[1], a2);
        a2 = MFMA(hc0, vrh[0], a2);
        a2 = MFMA(hc0, vrl[0], a2);
        a2 = MFMA(hc1, vrh[1], a2);
        a2 = MFMA(hc1, vrl[1], a2);
        if ((lane & 15) < 2) {
#pragma unroll
            for (int r = 0; r < 4; ++r) {
                const long node = (long)rt * 16 + 4 * g + r;
                out[node * 2 + (lane & 15)] = a2[r] + bo2;
            }
        }
        // no trailing barrier: next iteration writes the other parity's sH
    }
}

extern "C" void kernel_launch(void* const* d_in, const int* in_sizes, int n_in,
                              void* d_out, int out_size, void* d_ws, size_t ws_size,
                              hipStream_t stream) {
    const float* x_c = (const float*)d_in[0];
    const float* x_m = (const float*)d_in[1];
    const int* cm_src = (const int*)d_in[2];
    const int* cm_dst = (const int*)d_in[3];
    const int* mc_src = (const int*)d_in[4];
    const int* mc_dst = (const int*)d_in[5];
    const float* Wl1_cm = (const float*)d_in[6];
    const float* Wr1_cm = (const float*)d_in[7];
    const float* b1_cm = (const float*)d_in[8];
    const float* Wl1_mc = (const float*)d_in[9];
    const float* Wr1_mc = (const float*)d_in[10];
    const float* b1_mc = (const float*)d_in[11];
    // layer-2 cm weights (d_in[12..14]) are dead: h2_m is unused in the reference
    const float* Wl2_mc = (const float*)d_in[15];
    const float* Wr2_mc = (const float*)d_in[16];
    const float* b2_mc = (const float*)d_in[17];
    const float* W_lin = (const float*)d_in[18];
    const float* b_lin = (const float*)d_in[19];
    float* out = (float*)d_out;

    // ---- workspace layout (~117 MB) ----
    unsigned short* up = (unsigned short*)d_ws;
    unsigned short* aggm16 = up;                        // NM*64
    unsigned short* hm16 = aggm16 + (long)NM * DF;      // NM*64
    unsigned short* xm16 = hm16 + (long)NM * DF;        // NM*64
    unsigned short* xc16 = xm16 + (long)NM * DF;        // NC*64
    unsigned short* meanx16 = xc16 + (long)NC * DF;     // NC*64
    unsigned short* meanh16 = meanx16 + (long)NC * DF;  // NC*64
    float* Vl = (float*)(meanh16 + (long)NC * DF);      // 64*16
    float* Vr = Vl + 64 * 16;                           // 64*16
    float* bo = Vr + 64 * 16;                           // 2 (+pad)
    int* ip = (int*)(bo + 4);

    int* startM = ip;                   // NM+1 (written by bp22)
    int* startC = startM + (NM + 1);    // NC+1 (written by bp22)
    int* cstartM = startC + (NC + 1);   // NBM+1
    int* cstartC = cstartM + (NBM + 1); // NBC+1
    int* ccurM = cstartC + (NBC + 1);   // NBM
    int* ccurC = ccurM + NBM;           // NBC
    int* pmM = ccurC + NBC;             // NSB*NBM
    int* pmC = pmM + NSB * NBM;         // NSB*NBC
    int* srt_cm = pmC + NSB * NBC;      // NE
    int* srt_mc = srt_cm + NE;          // NE
    int* bktM = srt_mc + NE;            // NE
    int* bktC = bktM + NE;              // NE

    // coarse hist + presplit + V-compose -> coarse scan -> sort -> fine offsets
    prep_k<<<2 * NSB + PSB + 1, 256, 0, stream>>>(cm_dst, mc_dst, pmM, pmC,
                                                  x_c, x_m, (u16x4*)xc16, (u16x4*)xm16,
                                                  Wl2_mc, Wr2_mc, b2_mc, W_lin, b_lin,
                                                  Vl, Vr, bo);
    cscan2_k<<<1, 256, 0, stream>>>(pmM, pmC, cstartM, cstartC, ccurM, ccurC);
    bsort2_k<<<2 * NSB, 256, 0, stream>>>(cm_src, cm_dst, mc_src, mc_dst,
                                          ccurM, ccurC, bktM, bktC);
    bp22_k<<<NBM + NBC, 256, 0, stream>>>(bktM, cstartM, startM, srt_cm,
                                          bktC, cstartC, startC, srt_mc);

    // layer 1 @ merchants: m-mean (bf16) then dense -> hm16
    agg16_k<<<NM / 16, 256, 0, stream>>>(xc16, startM, srt_cm, aggm16, NM);
    dense1nm_k<<<1024, 256, 0, stream>>>(aggm16, xm16, Wl1_cm, Wr1_cm, b1_cm, hm16, NM);

    // customers: fused dual aggregation (x_m-mean + h_m-mean in one edge sweep)
    aggc2_k<<<NC / 16, 256, 0, stream>>>(xm16, hm16, startC, srt_mc,
                                         meanx16, meanh16, NC);

    // customers: layer1 + folded layer2 (+W_lin) -> out (split from gather)
    densec_k<<<2048, 256, 0, stream>>>(meanx16, meanh16, xc16,
                                       Wl1_mc, Wr1_mc, b1_mc,
                                       Vl, Vr, bo, out, NC);
}

// Round 17
// 237.222 us; speedup vs baseline: 1.2519x; 1.0861x over previous
//
#include <hip/hip_runtime.h>

#define NC 200000
#define NM 50000
#define NE 1000000
#define DF 64   // feature dim (D == H == 64)

#define BSH 10
#define BW 1024
#define NBM ((NM + BW - 1) >> BSH)   // 49
#define NBC ((NC + BW - 1) >> BSH)   // 196
#define CH 4096                      // edges per chunk block
#define NSB ((NE + CH - 1) / CH)     // 245
#define PSB 1024                     // presplit blocks inside prep_k

typedef __attribute__((ext_vector_type(8))) short bf16x8;
typedef __attribute__((ext_vector_type(4))) float f32x4;
typedef __attribute__((ext_vector_type(4))) unsigned short u16x4;

// ---------------- round-to-nearest bf16 helpers ----------------
__device__ __forceinline__ short bf16rn(float x) {
    unsigned u = __builtin_bit_cast(unsigned, x);
    unsigned r = u + 0x7FFFu + ((u >> 16) & 1u);
    return (short)(r >> 16);
}
__device__ __forceinline__ float bf16f(short h) {
    unsigned u = ((unsigned)(unsigned short)h) << 16;
    return __builtin_bit_cast(float, u);
}
__device__ __forceinline__ void split8(const f32x4 u, const f32x4 v,
                                       bf16x8& hi, bf16x8& lo) {
#pragma unroll
    for (int b = 0; b < 4; ++b) {
        short h = bf16rn(u[b]);
        hi[b] = h;
        lo[b] = bf16rn(u[b] - bf16f(h));
    }
#pragma unroll
    for (int b = 0; b < 4; ++b) {
        short h = bf16rn(v[b]);
        hi[4 + b] = h;
        lo[4 + b] = bf16rn(v[b] - bf16f(h));
    }
}

// ---------------- wave-wide inclusive scan (64 lanes, no barriers) ----------------
__device__ __forceinline__ int wscan_incl(int v, int lane) {
#pragma unroll
    for (int off = 1; off < 64; off <<= 1) {
        int y = __shfl_up(v, off);
        if (lane >= off) v += y;
    }
    return v;
}

// ---- prep: coarse hists (no global atomics) + bf16 presplit + W_lin folding ------
__global__ __launch_bounds__(256) void prep_k(const int* __restrict__ cm_dst,
                                              const int* __restrict__ mc_dst,
                                              int* __restrict__ pmM,
                                              int* __restrict__ pmC,
                                              const float* __restrict__ x_c,
                                              const float* __restrict__ x_m,
                                              u16x4* __restrict__ xc16,
                                              u16x4* __restrict__ xm16,
                                              const float* __restrict__ Wl2,
                                              const float* __restrict__ Wr2,
                                              const float* __restrict__ b2,
                                              const float* __restrict__ Wlin,
                                              const float* __restrict__ blin,
                                              float* __restrict__ Vl,
                                              float* __restrict__ Vr,
                                              float* __restrict__ bo) {
    __shared__ int cnt[256];
    const int t = threadIdx.x;
    if (blockIdx.x < 2 * NSB) {
        const int side = (blockIdx.x >= NSB);
        const int blk = blockIdx.x - side * NSB;
        const int* dst = side ? mc_dst : cm_dst;
        int* pm = side ? pmC : pmM;
        const int nb = side ? NBC : NBM;
        cnt[t] = 0;
        __syncthreads();
        const int e0 = blk * CH;
        const int n = min(CH, NE - e0);
        for (int i = t; i < n; i += 256) atomicAdd(&cnt[dst[e0 + i] >> BSH], 1);
        __syncthreads();
        if (t < nb) pm[(long)blk * nb + t] = cnt[t];
    } else if (blockIdx.x < 2 * NSB + PSB) {
        const int blk = blockIdx.x - 2 * NSB;
        const int NC4 = NC * (DF / 4);
        const int NT4 = (NC + NM) * (DF / 4);
        const int st = PSB * 256;
        for (int i = blk * 256 + t; i < NT4; i += st) {
            const bool isc = (i < NC4);
            const int j = isc ? i : i - NC4;
            const f32x4 v = isc ? ((const f32x4*)x_c)[j] : ((const f32x4*)x_m)[j];
            u16x4 o;
#pragma unroll
            for (int b = 0; b < 4; ++b) o[b] = (unsigned short)bf16rn(v[b]);
            if (isc) xc16[j] = o;
            else     xm16[j] = o;
        }
    } else {
        // compose Vl = Wl2@Wlin, Vr = Wr2@Wlin (64x2 padded to 64x16), bo = b2@Wlin+blin
        for (int i = t; i < 2 * 64 * 16; i += 256) {
            float* dst = (i < 1024) ? Vl : Vr;
            dst[i & 1023] = 0.0f;
        }
        __syncthreads();
        if (t < 128) {
            const int k = t >> 1, o = t & 1;
            float sl = 0.f, sr = 0.f;
            for (int j = 0; j < 64; ++j) {
                sl += Wl2[k * 64 + j] * Wlin[j * 2 + o];
                sr += Wr2[k * 64 + j] * Wlin[j * 2 + o];
            }
            Vl[k * 16 + o] = sl;
            Vr[k * 16 + o] = sr;
        }
        if (t < 2) {
            float s = blin[t];
            for (int j = 0; j < 64; ++j) s += b2[j] * Wlin[j * 2 + t];
            bo[t] = s;
        }
    }
}

// ---------------- coarse reduce+scan (one tiny block): cstart + ccur init ----------
__global__ __launch_bounds__(256) void cscan2_k(const int* __restrict__ pmM,
                                                const int* __restrict__ pmC,
                                                int* __restrict__ cstartM,
                                                int* __restrict__ cstartC,
                                                int* __restrict__ ccurM,
                                                int* __restrict__ ccurC) {
    __shared__ int wsum[4];
    const int t = threadIdx.x, lane = t & 63, wv = t >> 6;
    int s = 0;
    if (t < NBM)
        for (int b = 0; b < NSB; ++b) s += pmM[(long)b * NBM + t];
    int incl = wscan_incl(s, lane);
    if (lane == 63) wsum[wv] = incl;
    __syncthreads();
    int wadd = 0;
#pragma unroll
    for (int w = 0; w < 4; ++w) wadd += (w < wv) ? wsum[w] : 0;
    const int tot = incl + wadd;
    if (t < NBM) { cstartM[t] = tot - s; ccurM[t] = tot - s; }
    if (t == NBM - 1) cstartM[NBM] = tot;
    __syncthreads();
    int s2 = 0;
    if (t < NBC)
        for (int b = 0; b < NSB; ++b) s2 += pmC[(long)b * NBC + t];
    int incl2 = wscan_incl(s2, lane);
    if (lane == 63) wsum[wv] = incl2;
    __syncthreads();
    int wadd2 = 0;
#pragma unroll
    for (int w = 0; w < 4; ++w) wadd2 += (w < wv) ? wsum[w] : 0;
    const int tot2 = incl2 + wadd2;
    if (t < NBC) { cstartC[t] = tot2 - s2; ccurC[t] = tot2 - s2; }
    if (t == NBC - 1) cstartC[NBC] = tot2;
}

// ---------------- bucket sort pass 1: LDS-staged, block-aggregated cursors ----------
__global__ __launch_bounds__(256) void bsort2_k(const int* __restrict__ cm_src,
                                                const int* __restrict__ cm_dst,
                                                const int* __restrict__ mc_src,
                                                const int* __restrict__ mc_dst,
                                                int* __restrict__ ccurM,
                                                int* __restrict__ ccurC,
                                                int* __restrict__ bktM,
                                                int* __restrict__ bktC) {
    __shared__ int cnt[256], pfx[256], gbase[256];
    __shared__ int wsum[4];
    __shared__ int stage[CH];
    const int side = (blockIdx.x >= NSB);
    const int blk = blockIdx.x - side * NSB;
    const int* src = side ? mc_src : cm_src;
    const int* dst = side ? mc_dst : cm_dst;
    int* ccur = side ? ccurC : ccurM;
    int* bkt = side ? bktC : bktM;
    const int nb = side ? NBC : NBM;

    const int t = threadIdx.x, lane = t & 63, wv = t >> 6;
    const int e0 = blk * CH;
    const int n = min(CH, NE - e0);
    cnt[t] = 0;
    __syncthreads();
    for (int i = t; i < n; i += 256) atomicAdd(&cnt[dst[e0 + i] >> BSH], 1);
    __syncthreads();
    const int myc = (t < nb) ? cnt[t] : 0;
    int incl = wscan_incl(myc, lane);
    if (lane == 63) wsum[wv] = incl;
    __syncthreads();
    int wadd = 0;
#pragma unroll
    for (int w = 0; w < 4; ++w) wadd += (w < wv) ? wsum[w] : 0;
    const int excl = wadd + incl - myc;
    if (t < nb && myc > 0) gbase[t] = atomicAdd(&ccur[t], myc);
    pfx[t] = excl;
    cnt[t] = 0;
    __syncthreads();
    for (int i = t; i < n; i += 256) {
        const int d = dst[e0 + i];
        const int b = d >> BSH;
        const int p = pfx[b] + atomicAdd(&cnt[b], 1);
        stage[p] = (src[e0 + i] << BSH) | (d & (BW - 1));
    }
    __syncthreads();
    for (int b = wv; b < nb; b += 4) {
        const int c = cnt[b];
        if (c == 0) continue;
        const int gb = gbase[b], lo = pfx[b];
        for (int j = lane; j < c; j += 64) bkt[gb + j] = stage[lo + j];
    }
}

// ---------------- bucket sort pass 2 + fine-offset construction ----------------
__global__ __launch_bounds__(256) void bp22_k(const int* __restrict__ bktM,
                                              const int* __restrict__ cstartM,
                                              int* __restrict__ startM,
                                              int* __restrict__ srtM,
                                              const int* __restrict__ bktC,
                                              const int* __restrict__ cstartC,
                                              int* __restrict__ startC,
                                              int* __restrict__ srtC) {
    __shared__ int lcur[BW];
    __shared__ int wsum[4];
    const int side = (blockIdx.x >= NBM);
    const int blk = blockIdx.x - side * NBM;
    const int* bkt = side ? bktC : bktM;
    const int* cstart = side ? cstartC : cstartM;
    int* start = side ? startC : startM;
    int* srt = side ? srtC : srtM;
    const int n_nodes = side ? NC : NM;
    const int base = blk << BSH;
    const int t = threadIdx.x, lane = t & 63, wv = t >> 6;

    const int e0 = cstart[blk];
    const int e1 = cstart[blk + 1];

    for (int i = t; i < BW; i += 256) lcur[i] = 0;
    __syncthreads();
    for (int e = e0 + t; e < e1; e += 256) atomicAdd(&lcur[bkt[e] & (BW - 1)], 1);
    __syncthreads();

    const int c0 = lcur[4 * t + 0], c1 = lcur[4 * t + 1];
    const int c2 = lcur[4 * t + 2], c3 = lcur[4 * t + 3];
    const int local = c0 + c1 + c2 + c3;
    int incl = wscan_incl(local, lane);
    if (lane == 63) wsum[wv] = incl;
    __syncthreads();
    int wadd = 0;
#pragma unroll
    for (int w = 0; w < 4; ++w) wadd += (w < wv) ? wsum[w] : 0;
    const int p0 = e0 + wadd + incl - local;
    const int p1 = p0 + c0, p2 = p1 + c1, p3 = p2 + c2;
    lcur[4 * t + 0] = p0;
    lcur[4 * t + 1] = p1;
    lcur[4 * t + 2] = p2;
    lcur[4 * t + 3] = p3;
    if (base + 4 * t + 0 < n_nodes) start[base + 4 * t + 0] = p0;
    if (base + 4 * t + 1 < n_nodes) start[base + 4 * t + 1] = p1;
    if (base + 4 * t + 2 < n_nodes) start[base + 4 * t + 2] = p2;
    if (base + 4 * t + 3 < n_nodes) start[base + 4 * t + 3] = p3;
    if (t == 0 && base + BW >= n_nodes) start[n_nodes] = e1;
    __syncthreads();

    for (int e = e0 + t; e < e1; e += 256) {
        const int p = bkt[e];
        const int pos = atomicAdd(&lcur[p & (BW - 1)], 1);
        srt[pos] = p >> BSH;
    }
}

// ---------------- single-plane aggregation: 16-lane subgroup per node ----------------
__global__ __launch_bounds__(256) void agg16_k(const unsigned short* __restrict__ xhi,
                                               const int* __restrict__ start,
                                               const int* __restrict__ srt,
                                               unsigned short* __restrict__ mean16,
                                               int n_nodes) {
    const int sgid = (blockIdx.x * blockDim.x + threadIdx.x) >> 4;
    const int nsg = (gridDim.x * blockDim.x) >> 4;
    const int k4 = (threadIdx.x & 15) * 4;
    for (int n = sgid; n < n_nodes; n += nsg) {
        const int s0 = start[n], s1 = start[n + 1];
        f32x4 a0 = {0.f, 0.f, 0.f, 0.f}, a1 = {0.f, 0.f, 0.f, 0.f};
        f32x4 a2 = {0.f, 0.f, 0.f, 0.f}, a3 = {0.f, 0.f, 0.f, 0.f};
        int e = s0;
        for (; e + 3 < s1; e += 4) {
            const int i0 = srt[e + 0], i1 = srt[e + 1];
            const int i2 = srt[e + 2], i3 = srt[e + 3];
            const u16x4 v0 = *(const u16x4*)(xhi + (long)i0 * DF + k4);
            const u16x4 v1 = *(const u16x4*)(xhi + (long)i1 * DF + k4);
            const u16x4 v2 = *(const u16x4*)(xhi + (long)i2 * DF + k4);
            const u16x4 v3 = *(const u16x4*)(xhi + (long)i3 * DF + k4);
#pragma unroll
            for (int c = 0; c < 4; ++c) {
                a0[c] += bf16f((short)v0[c]);
                a1[c] += bf16f((short)v1[c]);
                a2[c] += bf16f((short)v2[c]);
                a3[c] += bf16f((short)v3[c]);
            }
        }
        for (; e < s1; ++e) {
            const int i0 = srt[e];
            const u16x4 v0 = *(const u16x4*)(xhi + (long)i0 * DF + k4);
#pragma unroll
            for (int c = 0; c < 4; ++c) a0[c] += bf16f((short)v0[c]);
        }
        const float inv = 1.0f / fmaxf((float)(s1 - s0), 1.0f);
        u16x4 o;
#pragma unroll
        for (int c = 0; c < 4; ++c)
            o[c] = (unsigned short)bf16rn(((a0[c] + a1[c]) + (a2[c] + a3[c])) * inv);
        *(u16x4*)(mean16 + (long)n * DF + k4) = o;
    }
}

// ---------------- dual aggregation over mc edges: x-plane rows + z pairs ----------
// z is 2 floats/merchant (400KB, L2-resident) -> broadcast load, no second row gather.
__global__ __launch_bounds__(256) void aggc2_k(const unsigned short* __restrict__ xp,
                                               const float* __restrict__ zm,
                                               const int* __restrict__ start,
                                               const int* __restrict__ srt,
                                               unsigned short* __restrict__ mx,
                                               float* __restrict__ mz, int n_nodes) {
    const int sgid = (blockIdx.x * blockDim.x + threadIdx.x) >> 4;
    const int nsg = (gridDim.x * blockDim.x) >> 4;
    const int k4 = (threadIdx.x & 15) * 4;
    for (int n = sgid; n < n_nodes; n += nsg) {
        const int s0 = start[n], s1 = start[n + 1];
        f32x4 ax0 = {0.f, 0.f, 0.f, 0.f}, ax1 = {0.f, 0.f, 0.f, 0.f};
        float z0 = 0.f, z1 = 0.f;
        int e = s0;
        for (; e + 1 < s1; e += 2) {
            const int iA = srt[e], iB = srt[e + 1];
            const u16x4 vxA = *(const u16x4*)(xp + (long)iA * DF + k4);
            const u16x4 vxB = *(const u16x4*)(xp + (long)iB * DF + k4);
            const float2 zA = *(const float2*)(zm + (long)iA * 2);
            const float2 zB = *(const float2*)(zm + (long)iB * 2);
#pragma unroll
            for (int c = 0; c < 4; ++c) {
                ax0[c] += bf16f((short)vxA[c]);
                ax1[c] += bf16f((short)vxB[c]);
            }
            z0 += zA.x + zB.x;
            z1 += zA.y + zB.y;
        }
        if (e < s1) {
            const int iA = srt[e];
            const u16x4 vxA = *(const u16x4*)(xp + (long)iA * DF + k4);
            const float2 zA = *(const float2*)(zm + (long)iA * 2);
#pragma unroll
            for (int c = 0; c < 4; ++c) ax0[c] += bf16f((short)vxA[c]);
            z0 += zA.x;
            z1 += zA.y;
        }
        const float inv = 1.0f / fmaxf((float)(s1 - s0), 1.0f);
        u16x4 ox;
#pragma unroll
        for (int c = 0; c < 4; ++c)
            ox[c] = (unsigned short)bf16rn((ax0[c] + ax1[c]) * inv);
        *(u16x4*)(mx + (long)n * DF + k4) = ox;
        if ((threadIdx.x & 15) == 0) {
            mz[(long)n * 2 + 0] = z0 * inv;
            mz[(long)n * 2 + 1] = z1 * inv;
        }
    }
}

#define MFMA(a, b, c) __builtin_amdgcn_mfma_f32_16x16x32_bf16((a), (b), (c), 0, 0, 0)

#define LOAD_W(Wl, Wr, col, g, wlh, wll, wrh, wrl)          \
    do {                                                    \
        _Pragma("unroll")                                   \
        for (int q = 0; q < 2; ++q) {                       \
            f32x4 tl0, tl1, tr0, tr1;                       \
            _Pragma("unroll")                               \
            for (int b = 0; b < 4; ++b) {                   \
                int k = 32 * q + 8 * (g) + b;               \
                tl0[b] = (Wl)[k * DF + (col)];              \
                tr0[b] = (Wr)[k * DF + (col)];              \
                tl1[b] = (Wl)[(k + 4) * DF + (col)];        \
                tr1[b] = (Wr)[(k + 4) * DF + (col)];        \
            }                                               \
            split8(tl0, tl1, wlh[q], wll[q]);               \
            split8(tr0, tr1, wrh[q], wrl[q]);               \
        }                                                   \
    } while (0)

// single V matrix, stride 16 (composed 64x2-in-64x16)
#define LOAD_V(V, col, g, vh, vlo)                          \
    do {                                                    \
        _Pragma("unroll")                                   \
        for (int q = 0; q < 2; ++q) {                       \
            f32x4 t0, t1;                                   \
            _Pragma("unroll")                               \
            for (int b = 0; b < 4; ++b) {                   \
                int k = 32 * q + 8 * (g) + b;               \
                t0[b] = (V)[k * 16 + (col)];                \
                t1[b] = (V)[(k + 4) * 16 + (col)];          \
            }                                               \
            split8(t0, t1, vh[q], vlo[q]);                  \
        }                                                   \
    } while (0)

// ---------------- dense1 @ NM: z = relu(mean@Wl + xm@Wr + b) @ Vl (2 floats/node) ----
__global__ __launch_bounds__(256) void dense1nm_k(const unsigned short* __restrict__ mean16,
                                                  const unsigned short* __restrict__ xm16,
                                                  const float* __restrict__ Wl,
                                                  const float* __restrict__ Wr,
                                                  const float* __restrict__ bias,
                                                  const float* __restrict__ Vl,
                                                  float* __restrict__ zm,
                                                  int n_nodes) {
    __shared__ float sZ[2][4][16][2];
    const int t = threadIdx.x;
    const int lane = t & 63;
    const int wv = t >> 6;
    const int col = wv * 16 + (lane & 15);
    const int g = lane >> 4;

    bf16x8 wlh[2], wll[2], wrh[2], wrl[2];
    LOAD_W(Wl, Wr, col, g, wlh, wll, wrh, wrl);
    const float bv = bias[col];
    const float vl0 = Vl[col * 16 + 0];
    const float vl1 = Vl[col * 16 + 1];

    const int nrt = n_nodes >> 4;
    int par = 0;
    for (int rt = blockIdx.x; rt < nrt; rt += gridDim.x, par ^= 1) {
        const long rowA = (long)rt * 16 + (lane & 15);
        const bf16x8 m0 = *(const bf16x8*)(mean16 + rowA * DF + 8 * g);
        const bf16x8 m1 = *(const bf16x8*)(mean16 + rowA * DF + 32 + 8 * g);
        const bf16x8 x0 = *(const bf16x8*)(xm16 + rowA * DF + 8 * g);
        const bf16x8 x1 = *(const bf16x8*)(xm16 + rowA * DF + 32 + 8 * g);
        f32x4 acc = {0.f, 0.f, 0.f, 0.f};
        acc = MFMA(m0, wlh[0], acc);
        acc = MFMA(m0, wll[0], acc);
        acc = MFMA(m1, wlh[1], acc);
        acc = MFMA(m1, wll[1], acc);
        acc = MFMA(x0, wrh[0], acc);
        acc = MFMA(x0, wrl[0], acc);
        acc = MFMA(x1, wrh[1], acc);
        acc = MFMA(x1, wrl[1], acc);

        // fold h (f32, pre-rounding) through Vl -> per-row 2-float partials
        float z0[4], z1[4];
#pragma unroll
        for (int r = 0; r < 4; ++r) {
            const float h = fmaxf(acc[r] + bv, 0.0f);
            z0[r] = h * vl0;
            z1[r] = h * vl1;
        }
#pragma unroll
        for (int m = 1; m < 16; m <<= 1) {
#pragma unroll
            for (int r = 0; r < 4; ++r) {
                z0[r] += __shfl_xor(z0[r], m);
                z1[r] += __shfl_xor(z1[r], m);
            }
        }
        if ((lane & 15) == 0) {
#pragma unroll
            for (int r = 0; r < 4; ++r) {
                sZ[par][wv][4 * g + r][0] = z0[r];
                sZ[par][wv][4 * g + r][1] = z1[r];
            }
        }
        __syncthreads();
        if (t < 16) {
            const long node = (long)rt * 16 + t;
            const float a = sZ[par][0][t][0] + sZ[par][1][t][0] +
                            sZ[par][2][t][0] + sZ[par][3][t][0];
            const float b = sZ[par][0][t][1] + sZ[par][1][t][1] +
                            sZ[par][2][t][1] + sZ[par][3][t][1];
            zm[node * 2 + 0] = a;
            zm[node * 2 + 1] = b;
        }
        // parity: next iteration writes the other sZ buffer
    }
}

// ---------------- customer dense: layer1 + (h_c @ Vr + meanz + bo) -> out ----------
__global__ __launch_bounds__(256) void densec_k(const unsigned short* __restrict__ meanx,
                                                const float* __restrict__ meanz,
                                                const unsigned short* __restrict__ xc,
                                                const float* __restrict__ Wl1,
                                                const float* __restrict__ Wr1,
                                                const float* __restrict__ b1,
                                                const float* __restrict__ Vr,
                                                const float* __restrict__ bo,
                                                float* __restrict__ out, int n_nodes) {
    __shared__ unsigned short sH[2][16][72];
    const int t = threadIdx.x;
    const int lane = t & 63;
    const int wv = t >> 6;
    const int col = wv * 16 + (lane & 15);
    const int g = lane >> 4;

    bf16x8 w1lh[2], w1ll[2], w1rh[2], w1rl[2];
    LOAD_W(Wl1, Wr1, col, g, w1lh, w1ll, w1rh, w1rl);
    const float bv1 = b1[col];
    bf16x8 vrh[2], vrl[2];
    LOAD_V(Vr, (lane & 15), g, vrh, vrl);
    const int oc = lane & 15;   // output col (0,1 real)
    const float bo2 = (oc < 2) ? bo[oc] : 0.0f;

    const int nrt = n_nodes >> 4;
    int par = 0;
    for (int rt = blockIdx.x; rt < nrt; rt += gridDim.x, par ^= 1) {
        const long rowA = (long)rt * 16 + (lane & 15);
        const bf16x8 mx0 = *(const bf16x8*)(meanx + rowA * DF + 8 * g);
        const bf16x8 mx1 = *(const bf16x8*)(meanx + rowA * DF + 32 + 8 * g);
        const bf16x8 xc0 = *(const bf16x8*)(xc + rowA * DF + 8 * g);
        const bf16x8 xc1 = *(const bf16x8*)(xc + rowA * DF + 32 + 8 * g);
        // prefetch meanz for this tile (latency hidden under MFMAs)
        float mzv[4];
        if (oc < 2) {
#pragma unroll
            for (int r = 0; r < 4; ++r)
                mzv[r] = meanz[((long)rt * 16 + 4 * g + r) * 2 + oc];
        }

        // ---- layer 1: h_c = relu(meanx @ Wl1 + x_c @ Wr1 + b1) ----
        f32x4 acc = {0.f, 0.f, 0.f, 0.f};
        acc = MFMA(mx0, w1lh[0], acc);
        acc = MFMA(mx0, w1ll[0], acc);
        acc = MFMA(mx1, w1lh[1], acc);
        acc = MFMA(mx1, w1ll[1], acc);
        acc = MFMA(xc0, w1rh[0], acc);
        acc = MFMA(xc0, w1rl[0], acc);
        acc = MFMA(xc1, w1rh[1], acc);
        acc = MFMA(xc1, w1rl[1], acc);
#pragma unroll
        for (int r = 0; r < 4; ++r)
            sH[par][4 * g + r][col] = (unsigned short)bf16rn(fmaxf(acc[r] + bv1, 0.0f));
        __syncthreads();

        // ---- folded layer 2: out = h_c @ Vr + meanz + bo (cols 0,1 real) ----
        const bf16x8 hc0 = *(const bf16x8*)&sH[par][lane & 15][8 * g];
        const bf16x8 hc1 = *(const bf16x8*)&sH[par][lane & 15][32 + 8 * g];
        f32x4 a2 = {0.f, 0.f, 0.f, 0.f};
        a2 = MFMA(hc0, vrh[0], a2);
        a2 = MFMA(hc0, vrl[0], a2);
        a2 = MFMA(hc1, vrh[1], a2);
        a2 = MFMA(hc1, vrl[1], a2);
        if (oc < 2) {
#pragma unroll
            for (int r = 0; r < 4; ++r) {
                const long node = (long)rt * 16 + 4 * g + r;
                out[node * 2 + oc] = a2[r] + mzv[r] + bo2;
            }
        }
        // no trailing barrier: next iteration writes the other parity's sH
    }
}

extern "C" void kernel_launch(void* const* d_in, const int* in_sizes, int n_in,
                              void* d_out, int out_size, void* d_ws, size_t ws_size,
                              hipStream_t stream) {
    const float* x_c = (const float*)d_in[0];
    const float* x_m = (const float*)d_in[1];
    const int* cm_src = (const int*)d_in[2];
    const int* cm_dst = (const int*)d_in[3];
    const int* mc_src = (const int*)d_in[4];
    const int* mc_dst = (const int*)d_in[5];
    const float* Wl1_cm = (const float*)d_in[6];
    const float* Wr1_cm = (const float*)d_in[7];
    const float* b1_cm = (const float*)d_in[8];
    const float* Wl1_mc = (const float*)d_in[9];
    const float* Wr1_mc = (const float*)d_in[10];
    const float* b1_mc = (const float*)d_in[11];
    // layer-2 cm weights (d_in[12..14]) are dead: h2_m is unused in the reference
    const float* Wl2_mc = (const float*)d_in[15];
    const float* Wr2_mc = (const float*)d_in[16];
    const float* b2_mc = (const float*)d_in[17];
    const float* W_lin = (const float*)d_in[18];
    const float* b_lin = (const float*)d_in[19];
    float* out = (float*)d_out;

    // ---- workspace layout (~85 MB) ----
    unsigned short* up = (unsigned short*)d_ws;
    unsigned short* aggm16 = up;                        // NM*64
    unsigned short* xm16 = aggm16 + (long)NM * DF;      // NM*64
    unsigned short* xc16 = xm16 + (long)NM * DF;        // NC*64
    unsigned short* meanx16 = xc16 + (long)NC * DF;     // NC*64
    float* zm = (float*)(meanx16 + (long)NC * DF);      // NM*2
    float* meanz = zm + (long)NM * 2;                   // NC*2
    float* Vl = meanz + (long)NC * 2;                   // 64*16
    float* Vr = Vl + 64 * 16;                           // 64*16
    float* bo = Vr + 64 * 16;                           // 2 (+pad)
    int* ip = (int*)(bo + 4);

    int* startM = ip;                   // NM+1 (written by bp22)
    int* startC = startM + (NM + 1);    // NC+1 (written by bp22)
    int* cstartM = startC + (NC + 1);   // NBM+1
    int* cstartC = cstartM + (NBM + 1); // NBC+1
    int* ccurM = cstartC + (NBC + 1);   // NBM
    int* ccurC = ccurM + NBM;           // NBC
    int* pmM = ccurC + NBC;             // NSB*NBM
    int* pmC = pmM + NSB * NBM;         // NSB*NBC
    int* srt_cm = pmC + NSB * NBC;      // NE
    int* srt_mc = srt_cm + NE;          // NE
    int* bktM = srt_mc + NE;            // NE
    int* bktC = bktM + NE;              // NE

    // coarse hist + presplit + V-compose -> coarse scan -> sort -> fine offsets
    prep_k<<<2 * NSB + PSB + 1, 256, 0, stream>>>(cm_dst, mc_dst, pmM, pmC,
                                                  x_c, x_m, (u16x4*)xc16, (u16x4*)xm16,
                                                  Wl2_mc, Wr2_mc, b2_mc, W_lin, b_lin,
                                                  Vl, Vr, bo);
    cscan2_k<<<1, 256, 0, stream>>>(pmM, pmC, cstartM, cstartC, ccurM, ccurC);
    bsort2_k<<<2 * NSB, 256, 0, stream>>>(cm_src, cm_dst, mc_src, mc_dst,
                                          ccurM, ccurC, bktM, bktC);
    bp22_k<<<NBM + NBC, 256, 0, stream>>>(bktM, cstartM, startM, srt_cm,
                                          bktC, cstartC, startC, srt_mc);

    // layer 1 @ merchants: m-mean (bf16), then dense folded to z = h_m @ Vl (2 f32)
    agg16_k<<<NM / 16, 256, 0, stream>>>(xc16, startM, srt_cm, aggm16, NM);
    dense1nm_k<<<1024, 256, 0, stream>>>(aggm16, xm16, Wl1_cm, Wr1_cm, b1_cm,
                                         Vl, zm, NM);

    // customers: dual aggregation (x_m rows + z pairs) in one edge sweep
    aggc2_k<<<NC / 16, 256, 0, stream>>>(xm16, zm, startC, srt_mc,
                                         meanx16, meanz, NC);

    // customers: layer1 + folded layer2 (h_c @ Vr + meanz) -> out
    densec_k<<<2048, 256, 0, stream>>>(meanx16, meanz, xc16,
                                       Wl1_mc, Wr1_mc, b1_mc,
                                       Vr, bo, out, NC);
}

// Round 18
// 208.855 us; speedup vs baseline: 1.4219x; 1.1358x over previous
//
#include <hip/hip_runtime.h>

#define NC 200000
#define NM 50000
#define NE 1000000
#define DF 64   // feature dim (D == H == 64)

// per-side bucket geometry, balanced to ~5.1K edges/bucket on both sides
#define BSH_M 8
#define BW_M 256
#define NBM ((NM + BW_M - 1) >> BSH_M)   // 196 (cm: dst = merchants, deg ~20)
#define BSH_C 10
#define BW_C 1024
#define NBC ((NC + BW_C - 1) >> BSH_C)   // 196 (mc: dst = customers, deg ~5)
#define CH 4096                          // edges per chunk block
#define NSB ((NE + CH - 1) / CH)         // 245
#define PSB 1024                         // presplit blocks inside prep_k

typedef __attribute__((ext_vector_type(8))) short bf16x8;
typedef __attribute__((ext_vector_type(4))) float f32x4;
typedef __attribute__((ext_vector_type(4))) unsigned short u16x4;

// ---------------- round-to-nearest bf16 helpers ----------------
__device__ __forceinline__ short bf16rn(float x) {
    unsigned u = __builtin_bit_cast(unsigned, x);
    unsigned r = u + 0x7FFFu + ((u >> 16) & 1u);
    return (short)(r >> 16);
}
__device__ __forceinline__ float bf16f(short h) {
    unsigned u = ((unsigned)(unsigned short)h) << 16;
    return __builtin_bit_cast(float, u);
}
__device__ __forceinline__ void split8(const f32x4 u, const f32x4 v,
                                       bf16x8& hi, bf16x8& lo) {
#pragma unroll
    for (int b = 0; b < 4; ++b) {
        short h = bf16rn(u[b]);
        hi[b] = h;
        lo[b] = bf16rn(u[b] - bf16f(h));
    }
#pragma unroll
    for (int b = 0; b < 4; ++b) {
        short h = bf16rn(v[b]);
        hi[4 + b] = h;
        lo[4 + b] = bf16rn(v[b] - bf16f(h));
    }
}

// ---------------- wave-wide inclusive scan (64 lanes, no barriers) ----------------
__device__ __forceinline__ int wscan_incl(int v, int lane) {
#pragma unroll
    for (int off = 1; off < 64; off <<= 1) {
        int y = __shfl_up(v, off);
        if (lane >= off) v += y;
    }
    return v;
}

// ---- prep: coarse hists (no global atomics) + bf16 presplit + W_lin folding ------
__global__ __launch_bounds__(256) void prep_k(const int* __restrict__ cm_dst,
                                              const int* __restrict__ mc_dst,
                                              int* __restrict__ pmM,
                                              int* __restrict__ pmC,
                                              const float* __restrict__ x_c,
                                              const float* __restrict__ x_m,
                                              u16x4* __restrict__ xc16,
                                              u16x4* __restrict__ xm16,
                                              const float* __restrict__ Wl2,
                                              const float* __restrict__ Wr2,
                                              const float* __restrict__ b2,
                                              const float* __restrict__ Wlin,
                                              const float* __restrict__ blin,
                                              float* __restrict__ Vl,
                                              float* __restrict__ Vr,
                                              float* __restrict__ bo) {
    __shared__ int cnt[256];
    const int t = threadIdx.x;
    if (blockIdx.x < 2 * NSB) {
        const int side = (blockIdx.x >= NSB);
        const int blk = blockIdx.x - side * NSB;
        const int* dst = side ? mc_dst : cm_dst;
        int* pm = side ? pmC : pmM;
        const int nb = side ? NBC : NBM;
        const int bsh = side ? BSH_C : BSH_M;
        cnt[t] = 0;
        __syncthreads();
        const int e0 = blk * CH;
        const int n = min(CH, NE - e0);
        for (int i = t; i < n; i += 256) atomicAdd(&cnt[dst[e0 + i] >> bsh], 1);
        __syncthreads();
        if (t < nb) pm[(long)blk * nb + t] = cnt[t];
    } else if (blockIdx.x < 2 * NSB + PSB) {
        const int blk = blockIdx.x - 2 * NSB;
        const int NC4 = NC * (DF / 4);
        const int NT4 = (NC + NM) * (DF / 4);
        const int st = PSB * 256;
        for (int i = blk * 256 + t; i < NT4; i += st) {
            const bool isc = (i < NC4);
            const int j = isc ? i : i - NC4;
            const f32x4 v = isc ? ((const f32x4*)x_c)[j] : ((const f32x4*)x_m)[j];
            u16x4 o;
#pragma unroll
            for (int b = 0; b < 4; ++b) o[b] = (unsigned short)bf16rn(v[b]);
            if (isc) xc16[j] = o;
            else     xm16[j] = o;
        }
    } else {
        // compose Vl = Wl2@Wlin, Vr = Wr2@Wlin (64x2 padded to 64x16), bo = b2@Wlin+blin
        for (int i = t; i < 2 * 64 * 16; i += 256) {
            float* dst = (i < 1024) ? Vl : Vr;
            dst[i & 1023] = 0.0f;
        }
        __syncthreads();
        if (t < 128) {
            const int k = t >> 1, o = t & 1;
            float sl = 0.f, sr = 0.f;
            for (int j = 0; j < 64; ++j) {
                sl += Wl2[k * 64 + j] * Wlin[j * 2 + o];
                sr += Wr2[k * 64 + j] * Wlin[j * 2 + o];
            }
            Vl[k * 16 + o] = sl;
            Vr[k * 16 + o] = sr;
        }
        if (t < 2) {
            float s = blin[t];
            for (int j = 0; j < 64; ++j) s += b2[j] * Wlin[j * 2 + t];
            bo[t] = s;
        }
    }
}

// ---------------- coarse reduce+scan (one tiny block): cstart + ccur init ----------
__global__ __launch_bounds__(256) void cscan2_k(const int* __restrict__ pmM,
                                                const int* __restrict__ pmC,
                                                int* __restrict__ cstartM,
                                                int* __restrict__ cstartC,
                                                int* __restrict__ ccurM,
                                                int* __restrict__ ccurC) {
    __shared__ int wsum[4];
    const int t = threadIdx.x, lane = t & 63, wv = t >> 6;
    int s = 0;
    if (t < NBM)
        for (int b = 0; b < NSB; ++b) s += pmM[(long)b * NBM + t];
    int incl = wscan_incl(s, lane);
    if (lane == 63) wsum[wv] = incl;
    __syncthreads();
    int wadd = 0;
#pragma unroll
    for (int w = 0; w < 4; ++w) wadd += (w < wv) ? wsum[w] : 0;
    const int tot = incl + wadd;
    if (t < NBM) { cstartM[t] = tot - s; ccurM[t] = tot - s; }
    if (t == NBM - 1) cstartM[NBM] = tot;
    __syncthreads();
    int s2 = 0;
    if (t < NBC)
        for (int b = 0; b < NSB; ++b) s2 += pmC[(long)b * NBC + t];
    int incl2 = wscan_incl(s2, lane);
    if (lane == 63) wsum[wv] = incl2;
    __syncthreads();
    int wadd2 = 0;
#pragma unroll
    for (int w = 0; w < 4; ++w) wadd2 += (w < wv) ? wsum[w] : 0;
    const int tot2 = incl2 + wadd2;
    if (t < NBC) { cstartC[t] = tot2 - s2; ccurC[t] = tot2 - s2; }
    if (t == NBC - 1) cstartC[NBC] = tot2;
}

// ---------------- bucket sort pass 1: LDS-staged, block-aggregated cursors ----------
__global__ __launch_bounds__(256) void bsort2_k(const int* __restrict__ cm_src,
                                                const int* __restrict__ cm_dst,
                                                const int* __restrict__ mc_src,
                                                const int* __restrict__ mc_dst,
                                                int* __restrict__ ccurM,
                                                int* __restrict__ ccurC,
                                                int* __restrict__ bktM,
                                                int* __restrict__ bktC) {
    __shared__ int cnt[256], pfx[256], gbase[256];
    __shared__ int wsum[4];
    __shared__ int stage[CH];
    const int side = (blockIdx.x >= NSB);
    const int blk = blockIdx.x - side * NSB;
    const int* src = side ? mc_src : cm_src;
    const int* dst = side ? mc_dst : cm_dst;
    int* ccur = side ? ccurC : ccurM;
    int* bkt = side ? bktC : bktM;
    const int nb = side ? NBC : NBM;
    const int bsh = side ? BSH_C : BSH_M;
    const int bmask = (side ? BW_C : BW_M) - 1;

    const int t = threadIdx.x, lane = t & 63, wv = t >> 6;
    const int e0 = blk * CH;
    const int n = min(CH, NE - e0);
    cnt[t] = 0;
    __syncthreads();
    for (int i = t; i < n; i += 256) atomicAdd(&cnt[dst[e0 + i] >> bsh], 1);
    __syncthreads();
    const int myc = (t < nb) ? cnt[t] : 0;
    int incl = wscan_incl(myc, lane);
    if (lane == 63) wsum[wv] = incl;
    __syncthreads();
    int wadd = 0;
#pragma unroll
    for (int w = 0; w < 4; ++w) wadd += (w < wv) ? wsum[w] : 0;
    const int excl = wadd + incl - myc;
    if (t < nb && myc > 0) gbase[t] = atomicAdd(&ccur[t], myc);
    pfx[t] = excl;
    cnt[t] = 0;
    __syncthreads();
    for (int i = t; i < n; i += 256) {
        const int d = dst[e0 + i];
        const int b = d >> bsh;
        const int p = pfx[b] + atomicAdd(&cnt[b], 1);
        stage[p] = (src[e0 + i] << bsh) | (d & bmask);
    }
    __syncthreads();
    for (int b = wv; b < nb; b += 4) {
        const int c = cnt[b];
        if (c == 0) continue;
        const int gb = gbase[b], lo = pfx[b];
        for (int j = lane; j < c; j += 64) bkt[gb + j] = stage[lo + j];
    }
}

// ---------------- bucket sort pass 2 + fine-offset construction ----------------
__global__ __launch_bounds__(256) void bp22_k(const int* __restrict__ bktM,
                                              const int* __restrict__ cstartM,
                                              int* __restrict__ startM,
                                              int* __restrict__ srtM,
                                              const int* __restrict__ bktC,
                                              const int* __restrict__ cstartC,
                                              int* __restrict__ startC,
                                              int* __restrict__ srtC) {
    __shared__ int lcur[BW_C];   // max of the two widths
    __shared__ int wsum[4];
    const int side = (blockIdx.x >= NBM);
    const int blk = blockIdx.x - side * NBM;
    const int* bkt = side ? bktC : bktM;
    const int* cstart = side ? cstartC : cstartM;
    int* start = side ? startC : startM;
    int* srt = side ? srtC : srtM;
    const int n_nodes = side ? NC : NM;
    const int bw = side ? BW_C : BW_M;
    const int bsh = side ? BSH_C : BSH_M;
    const int base = blk << bsh;
    const int t = threadIdx.x, lane = t & 63, wv = t >> 6;

    const int e0 = cstart[blk];
    const int e1 = cstart[blk + 1];

    for (int i = t; i < bw; i += 256) lcur[i] = 0;
    __syncthreads();
    for (int e = e0 + t; e < e1; e += 256) atomicAdd(&lcur[bkt[e] & (bw - 1)], 1);
    __syncthreads();

    int c0 = 0, c1 = 0, c2 = 0, c3 = 0;
    const bool act = (4 * t < bw);
    if (act) {
        c0 = lcur[4 * t + 0]; c1 = lcur[4 * t + 1];
        c2 = lcur[4 * t + 2]; c3 = lcur[4 * t + 3];
    }
    const int local = c0 + c1 + c2 + c3;
    int incl = wscan_incl(local, lane);
    if (lane == 63) wsum[wv] = incl;
    __syncthreads();
    int wadd = 0;
#pragma unroll
    for (int w = 0; w < 4; ++w) wadd += (w < wv) ? wsum[w] : 0;
    const int p0 = e0 + wadd + incl - local;
    const int p1 = p0 + c0, p2 = p1 + c1, p3 = p2 + c2;
    if (act) {
        lcur[4 * t + 0] = p0;
        lcur[4 * t + 1] = p1;
        lcur[4 * t + 2] = p2;
        lcur[4 * t + 3] = p3;
        if (base + 4 * t + 0 < n_nodes) start[base + 4 * t + 0] = p0;
        if (base + 4 * t + 1 < n_nodes) start[base + 4 * t + 1] = p1;
        if (base + 4 * t + 2 < n_nodes) start[base + 4 * t + 2] = p2;
        if (base + 4 * t + 3 < n_nodes) start[base + 4 * t + 3] = p3;
    }
    if (t == 0 && base + bw >= n_nodes) start[n_nodes] = e1;
    __syncthreads();

    for (int e = e0 + t; e < e1; e += 256) {
        const int p = bkt[e];
        const int pos = atomicAdd(&lcur[p & (bw - 1)], 1);
        srt[pos] = p >> bsh;
    }
}

// ---------------- single-plane aggregation: 16-lane subgroup per node ----------------
__global__ __launch_bounds__(256) void agg16_k(const unsigned short* __restrict__ xhi,
                                               const int* __restrict__ start,
                                               const int* __restrict__ srt,
                                               unsigned short* __restrict__ mean16,
                                               int n_nodes) {
    const int sgid = (blockIdx.x * blockDim.x + threadIdx.x) >> 4;
    const int nsg = (gridDim.x * blockDim.x) >> 4;
    const int k4 = (threadIdx.x & 15) * 4;
    for (int n = sgid; n < n_nodes; n += nsg) {
        const int s0 = start[n], s1 = start[n + 1];
        f32x4 a0 = {0.f, 0.f, 0.f, 0.f}, a1 = {0.f, 0.f, 0.f, 0.f};
        f32x4 a2 = {0.f, 0.f, 0.f, 0.f}, a3 = {0.f, 0.f, 0.f, 0.f};
        int e = s0;
        for (; e + 3 < s1; e += 4) {
            const int i0 = srt[e + 0], i1 = srt[e + 1];
            const int i2 = srt[e + 2], i3 = srt[e + 3];
            const u16x4 v0 = *(const u16x4*)(xhi + (long)i0 * DF + k4);
            const u16x4 v1 = *(const u16x4*)(xhi + (long)i1 * DF + k4);
            const u16x4 v2 = *(const u16x4*)(xhi + (long)i2 * DF + k4);
            const u16x4 v3 = *(const u16x4*)(xhi + (long)i3 * DF + k4);
#pragma unroll
            for (int c = 0; c < 4; ++c) {
                a0[c] += bf16f((short)v0[c]);
                a1[c] += bf16f((short)v1[c]);
                a2[c] += bf16f((short)v2[c]);
                a3[c] += bf16f((short)v3[c]);
            }
        }
        for (; e < s1; ++e) {
            const int i0 = srt[e];
            const u16x4 v0 = *(const u16x4*)(xhi + (long)i0 * DF + k4);
#pragma unroll
            for (int c = 0; c < 4; ++c) a0[c] += bf16f((short)v0[c]);
        }
        const float inv = 1.0f / fmaxf((float)(s1 - s0), 1.0f);
        u16x4 o;
#pragma unroll
        for (int c = 0; c < 4; ++c)
            o[c] = (unsigned short)bf16rn(((a0[c] + a1[c]) + (a2[c] + a3[c])) * inv);
        *(u16x4*)(mean16 + (long)n * DF + k4) = o;
    }
}

// ---------------- dual aggregation over mc edges: x-plane rows + z pairs ----------
__global__ __launch_bounds__(256) void aggc2_k(const unsigned short* __restrict__ xp,
                                               const float* __restrict__ zm,
                                               const int* __restrict__ start,
                                               const int* __restrict__ srt,
                                               unsigned short* __restrict__ mx,
                                               float* __restrict__ mz, int n_nodes) {
    const int sgid = (blockIdx.x * blockDim.x + threadIdx.x) >> 4;
    const int nsg = (gridDim.x * blockDim.x) >> 4;
    const int k4 = (threadIdx.x & 15) * 4;
    for (int n = sgid; n < n_nodes; n += nsg) {
        const int s0 = start[n], s1 = start[n + 1];
        f32x4 ax0 = {0.f, 0.f, 0.f, 0.f}, ax1 = {0.f, 0.f, 0.f, 0.f};
        float z0 = 0.f, z1 = 0.f;
        int e = s0;
        for (; e + 1 < s1; e += 2) {
            const int iA = srt[e], iB = srt[e + 1];
            const u16x4 vxA = *(const u16x4*)(xp + (long)iA * DF + k4);
            const u16x4 vxB = *(const u16x4*)(xp + (long)iB * DF + k4);
            const float2 zA = *(const float2*)(zm + (long)iA * 2);
            const float2 zB = *(const float2*)(zm + (long)iB * 2);
#pragma unroll
            for (int c = 0; c < 4; ++c) {
                ax0[c] += bf16f((short)vxA[c]);
                ax1[c] += bf16f((short)vxB[c]);
            }
            z0 += zA.x + zB.x;
            z1 += zA.y + zB.y;
        }
        if (e < s1) {
            const int iA = srt[e];
            const u16x4 vxA = *(const u16x4*)(xp + (long)iA * DF + k4);
            const float2 zA = *(const float2*)(zm + (long)iA * 2);
#pragma unroll
            for (int c = 0; c < 4; ++c) ax0[c] += bf16f((short)vxA[c]);
            z0 += zA.x;
            z1 += zA.y;
        }
        const float inv = 1.0f / fmaxf((float)(s1 - s0), 1.0f);
        u16x4 ox;
#pragma unroll
        for (int c = 0; c < 4; ++c)
            ox[c] = (unsigned short)bf16rn((ax0[c] + ax1[c]) * inv);
        *(u16x4*)(mx + (long)n * DF + k4) = ox;
        if ((threadIdx.x & 15) == 0) {
            mz[(long)n * 2 + 0] = z0 * inv;
            mz[(long)n * 2 + 1] = z1 * inv;
        }
    }
}

#define MFMA(a, b, c) __builtin_amdgcn_mfma_f32_16x16x32_bf16((a), (b), (c), 0, 0, 0)

#define LOAD_W(Wl, Wr, col, g, wlh, wll, wrh, wrl)          \
    do {                                                    \
        _Pragma("unroll")                                   \
        for (int q = 0; q < 2; ++q) {                       \
            f32x4 tl0, tl1, tr0, tr1;                       \
            _Pragma("unroll")                               \
            for (int b = 0; b < 4; ++b) {                   \
                int k = 32 * q + 8 * (g) + b;               \
                tl0[b] = (Wl)[k * DF + (col)];              \
                tr0[b] = (Wr)[k * DF + (col)];              \
                tl1[b] = (Wl)[(k + 4) * DF + (col)];        \
                tr1[b] = (Wr)[(k + 4) * DF + (col)];        \
            }                                               \
            split8(tl0, tl1, wlh[q], wll[q]);               \
            split8(tr0, tr1, wrh[q], wrl[q]);               \
        }                                                   \
    } while (0)

// single V matrix, stride 16 (composed 64x2-in-64x16)
#define LOAD_V(V, col, g, vh, vlo)                          \
    do {                                                    \
        _Pragma("unroll")                                   \
        for (int q = 0; q < 2; ++q) {                       \
            f32x4 t0, t1;                                   \
            _Pragma("unroll")                               \
            for (int b = 0; b < 4; ++b) {                   \
                int k = 32 * q + 8 * (g) + b;               \
                t0[b] = (V)[k * 16 + (col)];                \
                t1[b] = (V)[(k + 4) * 16 + (col)];          \
            }                                               \
            split8(t0, t1, vh[q], vlo[q]);                  \
        }                                                   \
    } while (0)

// ---------------- dense1 @ NM: z = relu(mean@Wl + xm@Wr + b) @ Vl (2 floats/node) ----
__global__ __launch_bounds__(256) void dense1nm_k(const unsigned short* __restrict__ mean16,
                                                  const unsigned short* __restrict__ xm16,
                                                  const float* __restrict__ Wl,
                                                  const float* __restrict__ Wr,
                                                  const float* __restrict__ bias,
                                                  const float* __restrict__ Vl,
                                                  float* __restrict__ zm,
                                                  int n_nodes) {
    __shared__ float sZ[2][4][16][2];
    const int t = threadIdx.x;
    const int lane = t & 63;
    const int wv = t >> 6;
    const int col = wv * 16 + (lane & 15);
    const int g = lane >> 4;

    bf16x8 wlh[2], wll[2], wrh[2], wrl[2];
    LOAD_W(Wl, Wr, col, g, wlh, wll, wrh, wrl);
    const float bv = bias[col];
    const float vl0 = Vl[col * 16 + 0];
    const float vl1 = Vl[col * 16 + 1];

    const int nrt = n_nodes >> 4;
    int par = 0;
    for (int rt = blockIdx.x; rt < nrt; rt += gridDim.x, par ^= 1) {
        const long rowA = (long)rt * 16 + (lane & 15);
        const bf16x8 m0 = *(const bf16x8*)(mean16 + rowA * DF + 8 * g);
        const bf16x8 m1 = *(const bf16x8*)(mean16 + rowA * DF + 32 + 8 * g);
        const bf16x8 x0 = *(const bf16x8*)(xm16 + rowA * DF + 8 * g);
        const bf16x8 x1 = *(const bf16x8*)(xm16 + rowA * DF + 32 + 8 * g);
        f32x4 acc = {0.f, 0.f, 0.f, 0.f};
        acc = MFMA(m0, wlh[0], acc);
        acc = MFMA(m0, wll[0], acc);
        acc = MFMA(m1, wlh[1], acc);
        acc = MFMA(m1, wll[1], acc);
        acc = MFMA(x0, wrh[0], acc);
        acc = MFMA(x0, wrl[0], acc);
        acc = MFMA(x1, wrh[1], acc);
        acc = MFMA(x1, wrl[1], acc);

        float z0[4], z1[4];
#pragma unroll
        for (int r = 0; r < 4; ++r) {
            const float h = fmaxf(acc[r] + bv, 0.0f);
            z0[r] = h * vl0;
            z1[r] = h * vl1;
        }
#pragma unroll
        for (int m = 1; m < 16; m <<= 1) {
#pragma unroll
            for (int r = 0; r < 4; ++r) {
                z0[r] += __shfl_xor(z0[r], m);
                z1[r] += __shfl_xor(z1[r], m);
            }
        }
        if ((lane & 15) == 0) {
#pragma unroll
            for (int r = 0; r < 4; ++r) {
                sZ[par][wv][4 * g + r][0] = z0[r];
                sZ[par][wv][4 * g + r][1] = z1[r];
            }
        }
        __syncthreads();
        if (t < 16) {
            const long node = (long)rt * 16 + t;
            const float a = sZ[par][0][t][0] + sZ[par][1][t][0] +
                            sZ[par][2][t][0] + sZ[par][3][t][0];
            const float b = sZ[par][0][t][1] + sZ[par][1][t][1] +
                            sZ[par][2][t][1] + sZ[par][3][t][1];
            zm[node * 2 + 0] = a;
            zm[node * 2 + 1] = b;
        }
    }
}

// ---------------- customer dense: layer1 + (h_c @ Vr + meanz + bo) -> out ----------
__global__ __launch_bounds__(256) void densec_k(const unsigned short* __restrict__ meanx,
                                                const float* __restrict__ meanz,
                                                const unsigned short* __restrict__ xc,
                                                const float* __restrict__ Wl1,
                                                const float* __restrict__ Wr1,
                                                const float* __restrict__ b1,
                                                const float* __restrict__ Vr,
                                                const float* __restrict__ bo,
                                                float* __restrict__ out, int n_nodes) {
    __shared__ unsigned short sH[2][16][72];
    const int t = threadIdx.x;
    const int lane = t & 63;
    const int wv = t >> 6;
    const int col = wv * 16 + (lane & 15);
    const int g = lane >> 4;

    bf16x8 w1lh[2], w1ll[2], w1rh[2], w1rl[2];
    LOAD_W(Wl1, Wr1, col, g, w1lh, w1ll, w1rh, w1rl);
    const float bv1 = b1[col];
    bf16x8 vrh[2], vrl[2];
    LOAD_V(Vr, (lane & 15), g, vrh, vrl);
    const int oc = lane & 15;
    const float bo2 = (oc < 2) ? bo[oc] : 0.0f;

    const int nrt = n_nodes >> 4;
    int par = 0;
    for (int rt = blockIdx.x; rt < nrt; rt += gridDim.x, par ^= 1) {
        const long rowA = (long)rt * 16 + (lane & 15);
        const bf16x8 mx0 = *(const bf16x8*)(meanx + rowA * DF + 8 * g);
        const bf16x8 mx1 = *(const bf16x8*)(meanx + rowA * DF + 32 + 8 * g);
        const bf16x8 xc0 = *(const bf16x8*)(xc + rowA * DF + 8 * g);
        const bf16x8 xc1 = *(const bf16x8*)(xc + rowA * DF + 32 + 8 * g);
        float mzv[4];
        if (oc < 2) {
#pragma unroll
            for (int r = 0; r < 4; ++r)
                mzv[r] = meanz[((long)rt * 16 + 4 * g + r) * 2 + oc];
        }

        f32x4 acc = {0.f, 0.f, 0.f, 0.f};
        acc = MFMA(mx0, w1lh[0], acc);
        acc = MFMA(mx0, w1ll[0], acc);
        acc = MFMA(mx1, w1lh[1], acc);
        acc = MFMA(mx1, w1ll[1], acc);
        acc = MFMA(xc0, w1rh[0], acc);
        acc = MFMA(xc0, w1rl[0], acc);
        acc = MFMA(xc1, w1rh[1], acc);
        acc = MFMA(xc1, w1rl[1], acc);
#pragma unroll
        for (int r = 0; r < 4; ++r)
            sH[par][4 * g + r][col] = (unsigned short)bf16rn(fmaxf(acc[r] + bv1, 0.0f));
        __syncthreads();

        const bf16x8 hc0 = *(const bf16x8*)&sH[par][lane & 15][8 * g];
        const bf16x8 hc1 = *(const bf16x8*)&sH[par][lane & 15][32 + 8 * g];
        f32x4 a2 = {0.f, 0.f, 0.f, 0.f};
        a2 = MFMA(hc0, vrh[0], a2);
        a2 = MFMA(hc0, vrl[0], a2);
        a2 = MFMA(hc1, vrh[1], a2);
        a2 = MFMA(hc1, vrl[1], a2);
        if (oc < 2) {
#pragma unroll
            for (int r = 0; r < 4; ++r) {
                const long node = (long)rt * 16 + 4 * g + r;
                out[node * 2 + oc] = a2[r] + mzv[r] + bo2;
            }
        }
    }
}

extern "C" void kernel_launch(void* const* d_in, const int* in_sizes, int n_in,
                              void* d_out, int out_size, void* d_ws, size_t ws_size,
                              hipStream_t stream) {
    const float* x_c = (const float*)d_in[0];
    const float* x_m = (const float*)d_in[1];
    const int* cm_src = (const int*)d_in[2];
    const int* cm_dst = (const int*)d_in[3];
    const int* mc_src = (const int*)d_in[4];
    const int* mc_dst = (const int*)d_in[5];
    const float* Wl1_cm = (const float*)d_in[6];
    const float* Wr1_cm = (const float*)d_in[7];
    const float* b1_cm = (const float*)d_in[8];
    const float* Wl1_mc = (const float*)d_in[9];
    const float* Wr1_mc = (const float*)d_in[10];
    const float* b1_mc = (const float*)d_in[11];
    // layer-2 cm weights (d_in[12..14]) are dead: h2_m is unused in the reference
    const float* Wl2_mc = (const float*)d_in[15];
    const float* Wr2_mc = (const float*)d_in[16];
    const float* b2_mc = (const float*)d_in[17];
    const float* W_lin = (const float*)d_in[18];
    const float* b_lin = (const float*)d_in[19];
    float* out = (float*)d_out;

    // ---- workspace layout (~85 MB) ----
    unsigned short* up = (unsigned short*)d_ws;
    unsigned short* aggm16 = up;                        // NM*64
    unsigned short* xm16 = aggm16 + (long)NM * DF;      // NM*64
    unsigned short* xc16 = xm16 + (long)NM * DF;        // NC*64
    unsigned short* meanx16 = xc16 + (long)NC * DF;     // NC*64
    float* zm = (float*)(meanx16 + (long)NC * DF);      // NM*2
    float* meanz = zm + (long)NM * 2;                   // NC*2
    float* Vl = meanz + (long)NC * 2;                   // 64*16
    float* Vr = Vl + 64 * 16;                           // 64*16
    float* bo = Vr + 64 * 16;                           // 2 (+pad)
    int* ip = (int*)(bo + 4);

    int* startM = ip;                   // NM+1 (written by bp22)
    int* startC = startM + (NM + 1);    // NC+1 (written by bp22)
    int* cstartM = startC + (NC + 1);   // NBM+1
    int* cstartC = cstartM + (NBM + 1); // NBC+1
    int* ccurM = cstartC + (NBC + 1);   // NBM
    int* ccurC = ccurM + NBM;           // NBC
    int* pmM = ccurC + NBC;             // NSB*NBM
    int* pmC = pmM + NSB * NBM;         // NSB*NBC
    int* srt_cm = pmC + NSB * NBC;      // NE
    int* srt_mc = srt_cm + NE;          // NE
    int* bktM = srt_mc + NE;            // NE
    int* bktC = bktM + NE;              // NE

    // coarse hist + presplit + V-compose -> coarse scan -> sort -> fine offsets
    prep_k<<<2 * NSB + PSB + 1, 256, 0, stream>>>(cm_dst, mc_dst, pmM, pmC,
                                                  x_c, x_m, (u16x4*)xc16, (u16x4*)xm16,
                                                  Wl2_mc, Wr2_mc, b2_mc, W_lin, b_lin,
                                                  Vl, Vr, bo);
    cscan2_k<<<1, 256, 0, stream>>>(pmM, pmC, cstartM, cstartC, ccurM, ccurC);
    bsort2_k<<<2 * NSB, 256, 0, stream>>>(cm_src, cm_dst, mc_src, mc_dst,
                                          ccurM, ccurC, bktM, bktC);
    bp22_k<<<NBM + NBC, 256, 0, stream>>>(bktM, cstartM, startM, srt_cm,
                                          bktC, cstartC, startC, srt_mc);

    // layer 1 @ merchants: m-mean (bf16), then dense folded to z = h_m @ Vl (2 f32)
    agg16_k<<<NM / 16, 256, 0, stream>>>(xc16, startM, srt_cm, aggm16, NM);
    dense1nm_k<<<1024, 256, 0, stream>>>(aggm16, xm16, Wl1_cm, Wr1_cm, b1_cm,
                                         Vl, zm, NM);

    // customers: dual aggregation (x_m rows + z pairs) in one edge sweep
    aggc2_k<<<NC / 16, 256, 0, stream>>>(xm16, zm, startC, srt_mc,
                                         meanx16, meanz, NC);

    // customers: layer1 + folded layer2 (h_c @ Vr + meanz) -> out
    densec_k<<<2048, 256, 0, stream>>>(meanx16, meanz, xc16,
                                       Wl1_mc, Wr1_mc, b1_mc,
                                       Vr, bo, out, NC);
}

// Round 19
// 176.256 us; speedup vs baseline: 1.6849x; 1.1850x over previous
//
#include <hip/hip_runtime.h>

#define NC 200000
#define NM 50000
#define NE 1000000
#define DF 64   // feature dim (D == H == 64)

// per-side bucket geometry, balanced to ~5.1K edges/bucket on both sides
#define BSH_M 8
#define BW_M 256
#define NBM ((NM + BW_M - 1) >> BSH_M)   // 196 (cm: dst = merchants, deg ~20)
#define BSH_C 10
#define BW_C 1024
#define NBC ((NC + BW_C - 1) >> BSH_C)   // 196 (mc: dst = customers, deg ~5)
#define CH 4096                          // edges per chunk block
#define NSB ((NE + CH - 1) / CH)         // 245
#define PSB 1024                         // presplit blocks inside prep_k

typedef __attribute__((ext_vector_type(8))) short bf16x8;
typedef __attribute__((ext_vector_type(4))) float f32x4;
typedef __attribute__((ext_vector_type(4))) unsigned short u16x4;

// ---------------- round-to-nearest bf16 helpers ----------------
__device__ __forceinline__ short bf16rn(float x) {
    unsigned u = __builtin_bit_cast(unsigned, x);
    unsigned r = u + 0x7FFFu + ((u >> 16) & 1u);
    return (short)(r >> 16);
}
__device__ __forceinline__ float bf16f(short h) {
    unsigned u = ((unsigned)(unsigned short)h) << 16;
    return __builtin_bit_cast(float, u);
}
__device__ __forceinline__ void split8(const f32x4 u, const f32x4 v,
                                       bf16x8& hi, bf16x8& lo) {
#pragma unroll
    for (int b = 0; b < 4; ++b) {
        short h = bf16rn(u[b]);
        hi[b] = h;
        lo[b] = bf16rn(u[b] - bf16f(h));
    }
#pragma unroll
    for (int b = 0; b < 4; ++b) {
        short h = bf16rn(v[b]);
        hi[4 + b] = h;
        lo[4 + b] = bf16rn(v[b] - bf16f(h));
    }
}

// ---------------- wave-wide inclusive scan (64 lanes, no barriers) ----------------
__device__ __forceinline__ int wscan_incl(int v, int lane) {
#pragma unroll
    for (int off = 1; off < 64; off <<= 1) {
        int y = __shfl_up(v, off);
        if (lane >= off) v += y;
    }
    return v;
}

// ---- prep: coarse hists (no global atomics) + bf16 presplit + W_lin folding ------
__global__ __launch_bounds__(256) void prep_k(const int* __restrict__ cm_dst,
                                              const int* __restrict__ mc_dst,
                                              int* __restrict__ pmM,
                                              int* __restrict__ pmC,
                                              const float* __restrict__ x_c,
                                              const float* __restrict__ x_m,
                                              u16x4* __restrict__ xc16,
                                              u16x4* __restrict__ xm16,
                                              const float* __restrict__ Wl2,
                                              const float* __restrict__ Wr2,
                                              const float* __restrict__ b2,
                                              const float* __restrict__ Wlin,
                                              const float* __restrict__ blin,
                                              float* __restrict__ Vl,
                                              float* __restrict__ Vr,
                                              float* __restrict__ bo) {
    __shared__ int cnt[256];
    const int t = threadIdx.x;
    if (blockIdx.x < 2 * NSB) {
        const int side = (blockIdx.x >= NSB);
        const int blk = blockIdx.x - side * NSB;
        const int* dst = side ? mc_dst : cm_dst;
        int* pm = side ? pmC : pmM;
        const int nb = side ? NBC : NBM;
        const int bsh = side ? BSH_C : BSH_M;
        cnt[t] = 0;
        __syncthreads();
        const int e0 = blk * CH;
        const int n = min(CH, NE - e0);
        for (int i = t; i < n; i += 256) atomicAdd(&cnt[dst[e0 + i] >> bsh], 1);
        __syncthreads();
        if (t < nb) pm[(long)blk * nb + t] = cnt[t];
    } else if (blockIdx.x < 2 * NSB + PSB) {
        const int blk = blockIdx.x - 2 * NSB;
        const int NC4 = NC * (DF / 4);
        const int NT4 = (NC + NM) * (DF / 4);
        const int st = PSB * 256;
        for (int i = blk * 256 + t; i < NT4; i += st) {
            const bool isc = (i < NC4);
            const int j = isc ? i : i - NC4;
            const f32x4 v = isc ? ((const f32x4*)x_c)[j] : ((const f32x4*)x_m)[j];
            u16x4 o;
#pragma unroll
            for (int b = 0; b < 4; ++b) o[b] = (unsigned short)bf16rn(v[b]);
            if (isc) xc16[j] = o;
            else     xm16[j] = o;
        }
    } else {
        // compose Vl = Wl2@Wlin, Vr = Wr2@Wlin (64x2 padded to 64x16), bo = b2@Wlin+blin
        for (int i = t; i < 2 * 64 * 16; i += 256) {
            float* dst = (i < 1024) ? Vl : Vr;
            dst[i & 1023] = 0.0f;
        }
        __syncthreads();
        if (t < 128) {
            const int k = t >> 1, o = t & 1;
            float sl = 0.f, sr = 0.f;
            for (int j = 0; j < 64; ++j) {
                sl += Wl2[k * 64 + j] * Wlin[j * 2 + o];
                sr += Wr2[k * 64 + j] * Wlin[j * 2 + o];
            }
            Vl[k * 16 + o] = sl;
            Vr[k * 16 + o] = sr;
        }
        if (t < 2) {
            float s = blin[t];
            for (int j = 0; j < 64; ++j) s += b2[j] * Wlin[j * 2 + t];
            bo[t] = s;
        }
    }
}

// ---------------- coarse reduce: one block per bucket, parallel over partials ------
__global__ __launch_bounds__(256) void cred2_k(const int* __restrict__ pmM,
                                               const int* __restrict__ pmC,
                                               int* __restrict__ totM,
                                               int* __restrict__ totC) {
    __shared__ int red[256];
    const int side = (blockIdx.x >= NBM);
    const int b = blockIdx.x - side * NBM;
    const int* pm = side ? pmC : pmM;
    const int nb = side ? NBC : NBM;
    int* tot = side ? totC : totM;
    const int t = threadIdx.x;
    int s = 0;
    for (int i = t; i < NSB; i += 256) s += pm[(long)i * nb + b];
    red[t] = s;
    __syncthreads();
    for (int off = 128; off > 0; off >>= 1) {
        if (t < off) red[t] += red[t + off];
        __syncthreads();
    }
    if (t == 0) tot[b] = red[0];
}

// ---------------- coarse scan over 392 totals (one tiny block) ----------------
__global__ __launch_bounds__(256) void cscan3_k(const int* __restrict__ totM,
                                                const int* __restrict__ totC,
                                                int* __restrict__ cstartM,
                                                int* __restrict__ cstartC,
                                                int* __restrict__ ccurM,
                                                int* __restrict__ ccurC) {
    __shared__ int wsum[4];
    const int t = threadIdx.x, lane = t & 63, wv = t >> 6;
    int s = (t < NBM) ? totM[t] : 0;
    int incl = wscan_incl(s, lane);
    if (lane == 63) wsum[wv] = incl;
    __syncthreads();
    int wadd = 0;
#pragma unroll
    for (int w = 0; w < 4; ++w) wadd += (w < wv) ? wsum[w] : 0;
    const int tot = incl + wadd;
    if (t < NBM) { cstartM[t] = tot - s; ccurM[t] = tot - s; }
    if (t == NBM - 1) cstartM[NBM] = tot;
    __syncthreads();
    int s2 = (t < NBC) ? totC[t] : 0;
    int incl2 = wscan_incl(s2, lane);
    if (lane == 63) wsum[wv] = incl2;
    __syncthreads();
    int wadd2 = 0;
#pragma unroll
    for (int w = 0; w < 4; ++w) wadd2 += (w < wv) ? wsum[w] : 0;
    const int tot2 = incl2 + wadd2;
    if (t < NBC) { cstartC[t] = tot2 - s2; ccurC[t] = tot2 - s2; }
    if (t == NBC - 1) cstartC[NBC] = tot2;
}

// ---------------- bucket sort pass 1: LDS-staged, block-aggregated cursors ----------
__global__ __launch_bounds__(256) void bsort2_k(const int* __restrict__ cm_src,
                                                const int* __restrict__ cm_dst,
                                                const int* __restrict__ mc_src,
                                                const int* __restrict__ mc_dst,
                                                int* __restrict__ ccurM,
                                                int* __restrict__ ccurC,
                                                int* __restrict__ bktM,
                                                int* __restrict__ bktC) {
    __shared__ int cnt[256], pfx[256], gbase[256];
    __shared__ int wsum[4];
    __shared__ int stage[CH];
    const int side = (blockIdx.x >= NSB);
    const int blk = blockIdx.x - side * NSB;
    const int* src = side ? mc_src : cm_src;
    const int* dst = side ? mc_dst : cm_dst;
    int* ccur = side ? ccurC : ccurM;
    int* bkt = side ? bktC : bktM;
    const int nb = side ? NBC : NBM;
    const int bsh = side ? BSH_C : BSH_M;
    const int bmask = (side ? BW_C : BW_M) - 1;

    const int t = threadIdx.x, lane = t & 63, wv = t >> 6;
    const int e0 = blk * CH;
    const int n = min(CH, NE - e0);
    cnt[t] = 0;
    __syncthreads();
    for (int i = t; i < n; i += 256) atomicAdd(&cnt[dst[e0 + i] >> bsh], 1);
    __syncthreads();
    const int myc = (t < nb) ? cnt[t] : 0;
    int incl = wscan_incl(myc, lane);
    if (lane == 63) wsum[wv] = incl;
    __syncthreads();
    int wadd = 0;
#pragma unroll
    for (int w = 0; w < 4; ++w) wadd += (w < wv) ? wsum[w] : 0;
    const int excl = wadd + incl - myc;
    if (t < nb && myc > 0) gbase[t] = atomicAdd(&ccur[t], myc);
    pfx[t] = excl;
    cnt[t] = 0;
    __syncthreads();
    for (int i = t; i < n; i += 256) {
        const int d = dst[e0 + i];
        const int b = d >> bsh;
        const int p = pfx[b] + atomicAdd(&cnt[b], 1);
        stage[p] = (src[e0 + i] << bsh) | (d & bmask);
    }
    __syncthreads();
    for (int b = wv; b < nb; b += 4) {
        const int c = cnt[b];
        if (c == 0) continue;
        const int gb = gbase[b], lo = pfx[b];
        for (int j = lane; j < c; j += 64) bkt[gb + j] = stage[lo + j];
    }
}

// ---------------- bucket sort pass 2 + fine-offset construction ----------------
__global__ __launch_bounds__(256) void bp22_k(const int* __restrict__ bktM,
                                              const int* __restrict__ cstartM,
                                              int* __restrict__ startM,
                                              int* __restrict__ srtM,
                                              const int* __restrict__ bktC,
                                              const int* __restrict__ cstartC,
                                              int* __restrict__ startC,
                                              int* __restrict__ srtC) {
    __shared__ int lcur[BW_C];   // max of the two widths
    __shared__ int wsum[4];
    const int side = (blockIdx.x >= NBM);
    const int blk = blockIdx.x - side * NBM;
    const int* bkt = side ? bktC : bktM;
    const int* cstart = side ? cstartC : cstartM;
    int* start = side ? startC : startM;
    int* srt = side ? srtC : srtM;
    const int n_nodes = side ? NC : NM;
    const int bw = side ? BW_C : BW_M;
    const int bsh = side ? BSH_C : BSH_M;
    const int base = blk << bsh;
    const int t = threadIdx.x, lane = t & 63, wv = t >> 6;

    const int e0 = cstart[blk];
    const int e1 = cstart[blk + 1];

    for (int i = t; i < bw; i += 256) lcur[i] = 0;
    __syncthreads();
    for (int e = e0 + t; e < e1; e += 256) atomicAdd(&lcur[bkt[e] & (bw - 1)], 1);
    __syncthreads();

    int c0 = 0, c1 = 0, c2 = 0, c3 = 0;
    const bool act = (4 * t < bw);
    if (act) {
        c0 = lcur[4 * t + 0]; c1 = lcur[4 * t + 1];
        c2 = lcur[4 * t + 2]; c3 = lcur[4 * t + 3];
    }
    const int local = c0 + c1 + c2 + c3;
    int incl = wscan_incl(local, lane);
    if (lane == 63) wsum[wv] = incl;
    __syncthreads();
    int wadd = 0;
#pragma unroll
    for (int w = 0; w < 4; ++w) wadd += (w < wv) ? wsum[w] : 0;
    const int p0 = e0 + wadd + incl - local;
    const int p1 = p0 + c0, p2 = p1 + c1, p3 = p2 + c2;
    if (act) {
        lcur[4 * t + 0] = p0;
        lcur[4 * t + 1] = p1;
        lcur[4 * t + 2] = p2;
        lcur[4 * t + 3] = p3;
        if (base + 4 * t + 0 < n_nodes) start[base + 4 * t + 0] = p0;
        if (base + 4 * t + 1 < n_nodes) start[base + 4 * t + 1] = p1;
        if (base + 4 * t + 2 < n_nodes) start[base + 4 * t + 2] = p2;
        if (base + 4 * t + 3 < n_nodes) start[base + 4 * t + 3] = p3;
    }
    if (t == 0 && base + bw >= n_nodes) start[n_nodes] = e1;
    __syncthreads();

    for (int e = e0 + t; e < e1; e += 256) {
        const int p = bkt[e];
        const int pos = atomicAdd(&lcur[p & (bw - 1)], 1);
        srt[pos] = p >> bsh;
    }
}

// ---------------- single-plane aggregation: 16-lane subgroup per node ----------------
__global__ __launch_bounds__(256) void agg16_k(const unsigned short* __restrict__ xhi,
                                               const int* __restrict__ start,
                                               const int* __restrict__ srt,
                                               unsigned short* __restrict__ mean16,
                                               int n_nodes) {
    const int sgid = (blockIdx.x * blockDim.x + threadIdx.x) >> 4;
    const int nsg = (gridDim.x * blockDim.x) >> 4;
    const int k4 = (threadIdx.x & 15) * 4;
    for (int n = sgid; n < n_nodes; n += nsg) {
        const int s0 = start[n], s1 = start[n + 1];
        f32x4 a0 = {0.f, 0.f, 0.f, 0.f}, a1 = {0.f, 0.f, 0.f, 0.f};
        f32x4 a2 = {0.f, 0.f, 0.f, 0.f}, a3 = {0.f, 0.f, 0.f, 0.f};
        int e = s0;
        for (; e + 3 < s1; e += 4) {
            const int i0 = srt[e + 0], i1 = srt[e + 1];
            const int i2 = srt[e + 2], i3 = srt[e + 3];
            const u16x4 v0 = *(const u16x4*)(xhi + (long)i0 * DF + k4);
            const u16x4 v1 = *(const u16x4*)(xhi + (long)i1 * DF + k4);
            const u16x4 v2 = *(const u16x4*)(xhi + (long)i2 * DF + k4);
            const u16x4 v3 = *(const u16x4*)(xhi + (long)i3 * DF + k4);
#pragma unroll
            for (int c = 0; c < 4; ++c) {
                a0[c] += bf16f((short)v0[c]);
                a1[c] += bf16f((short)v1[c]);
                a2[c] += bf16f((short)v2[c]);
                a3[c] += bf16f((short)v3[c]);
            }
        }
        for (; e < s1; ++e) {
            const int i0 = srt[e];
            const u16x4 v0 = *(const u16x4*)(xhi + (long)i0 * DF + k4);
#pragma unroll
            for (int c = 0; c < 4; ++c) a0[c] += bf16f((short)v0[c]);
        }
        const float inv = 1.0f / fmaxf((float)(s1 - s0), 1.0f);
        u16x4 o;
#pragma unroll
        for (int c = 0; c < 4; ++c)
            o[c] = (unsigned short)bf16rn(((a0[c] + a1[c]) + (a2[c] + a3[c])) * inv);
        *(u16x4*)(mean16 + (long)n * DF + k4) = o;
    }
}

// ---------------- dual aggregation over mc edges: x-plane rows + z pairs ----------
__global__ __launch_bounds__(256) void aggc2_k(const unsigned short* __restrict__ xp,
                                               const float* __restrict__ zm,
                                               const int* __restrict__ start,
                                               const int* __restrict__ srt,
                                               unsigned short* __restrict__ mx,
                                               float* __restrict__ mz, int n_nodes) {
    const int sgid = (blockIdx.x * blockDim.x + threadIdx.x) >> 4;
    const int nsg = (gridDim.x * blockDim.x) >> 4;
    const int k4 = (threadIdx.x & 15) * 4;
    for (int n = sgid; n < n_nodes; n += nsg) {
        const int s0 = start[n], s1 = start[n + 1];
        f32x4 ax0 = {0.f, 0.f, 0.f, 0.f}, ax1 = {0.f, 0.f, 0.f, 0.f};
        float z0 = 0.f, z1 = 0.f;
        int e = s0;
        for (; e + 1 < s1; e += 2) {
            const int iA = srt[e], iB = srt[e + 1];
            const u16x4 vxA = *(const u16x4*)(xp + (long)iA * DF + k4);
            const u16x4 vxB = *(const u16x4*)(xp + (long)iB * DF + k4);
            const float2 zA = *(const float2*)(zm + (long)iA * 2);
            const float2 zB = *(const float2*)(zm + (long)iB * 2);
#pragma unroll
            for (int c = 0; c < 4; ++c) {
                ax0[c] += bf16f((short)vxA[c]);
                ax1[c] += bf16f((short)vxB[c]);
            }
            z0 += zA.x + zB.x;
            z1 += zA.y + zB.y;
        }
        if (e < s1) {
            const int iA = srt[e];
            const u16x4 vxA = *(const u16x4*)(xp + (long)iA * DF + k4);
            const float2 zA = *(const float2*)(zm + (long)iA * 2);
#pragma unroll
            for (int c = 0; c < 4; ++c) ax0[c] += bf16f((short)vxA[c]);
            z0 += zA.x;
            z1 += zA.y;
        }
        const float inv = 1.0f / fmaxf((float)(s1 - s0), 1.0f);
        u16x4 ox;
#pragma unroll
        for (int c = 0; c < 4; ++c)
            ox[c] = (unsigned short)bf16rn((ax0[c] + ax1[c]) * inv);
        *(u16x4*)(mx + (long)n * DF + k4) = ox;
        if ((threadIdx.x & 15) == 0) {
            mz[(long)n * 2 + 0] = z0 * inv;
            mz[(long)n * 2 + 1] = z1 * inv;
        }
    }
}

#define MFMA(a, b, c) __builtin_amdgcn_mfma_f32_16x16x32_bf16((a), (b), (c), 0, 0, 0)

#define LOAD_W(Wl, Wr, col, g, wlh, wll, wrh, wrl)          \
    do {                                                    \
        _Pragma("unroll")                                   \
        for (int q = 0; q < 2; ++q) {                       \
            f32x4 tl0, tl1, tr0, tr1;                       \
            _Pragma("unroll")                               \
            for (int b = 0; b < 4; ++b) {                   \
                int k = 32 * q + 8 * (g) + b;               \
                tl0[b] = (Wl)[k * DF + (col)];              \
                tr0[b] = (Wr)[k * DF + (col)];              \
                tl1[b] = (Wl)[(k + 4) * DF + (col)];        \
                tr1[b] = (Wr)[(k + 4) * DF + (col)];        \
            }                                               \
            split8(tl0, tl1, wlh[q], wll[q]);               \
            split8(tr0, tr1, wrh[q], wrl[q]);               \
        }                                                   \
    } while (0)

// single V matrix, stride 16 (composed 64x2-in-64x16)
#define LOAD_V(V, col, g, vh, vlo)                          \
    do {                                                    \
        _Pragma("unroll")                                   \
        for (int q = 0; q < 2; ++q) {                       \
            f32x4 t0, t1;                                   \
            _Pragma("unroll")                               \
            for (int b = 0; b < 4; ++b) {                   \
                int k = 32 * q + 8 * (g) + b;               \
                t0[b] = (V)[k * 16 + (col)];                \
                t1[b] = (V)[(k + 4) * 16 + (col)];          \
            }                                               \
            split8(t0, t1, vh[q], vlo[q]);                  \
        }                                                   \
    } while (0)

// ---------------- dense1 @ NM: z = relu(mean@Wl + xm@Wr + b) @ Vl (2 floats/node) ----
__global__ __launch_bounds__(256) void dense1nm_k(const unsigned short* __restrict__ mean16,
                                                  const unsigned short* __restrict__ xm16,
                                                  const float* __restrict__ Wl,
                                                  const float* __restrict__ Wr,
                                                  const float* __restrict__ bias,
                                                  const float* __restrict__ Vl,
                                                  float* __restrict__ zm,
                                                  int n_nodes) {
    __shared__ float sZ[2][4][16][2];
    const int t = threadIdx.x;
    const int lane = t & 63;
    const int wv = t >> 6;
    const int col = wv * 16 + (lane & 15);
    const int g = lane >> 4;

    bf16x8 wlh[2], wll[2], wrh[2], wrl[2];
    LOAD_W(Wl, Wr, col, g, wlh, wll, wrh, wrl);
    const float bv = bias[col];
    const float vl0 = Vl[col * 16 + 0];
    const float vl1 = Vl[col * 16 + 1];

    const int nrt = n_nodes >> 4;
    int par = 0;
    for (int rt = blockIdx.x; rt < nrt; rt += gridDim.x, par ^= 1) {
        const long rowA = (long)rt * 16 + (lane & 15);
        const bf16x8 m0 = *(const bf16x8*)(mean16 + rowA * DF + 8 * g);
        const bf16x8 m1 = *(const bf16x8*)(mean16 + rowA * DF + 32 + 8 * g);
        const bf16x8 x0 = *(const bf16x8*)(xm16 + rowA * DF + 8 * g);
        const bf16x8 x1 = *(const bf16x8*)(xm16 + rowA * DF + 32 + 8 * g);
        f32x4 acc = {0.f, 0.f, 0.f, 0.f};
        acc = MFMA(m0, wlh[0], acc);
        acc = MFMA(m0, wll[0], acc);
        acc = MFMA(m1, wlh[1], acc);
        acc = MFMA(m1, wll[1], acc);
        acc = MFMA(x0, wrh[0], acc);
        acc = MFMA(x0, wrl[0], acc);
        acc = MFMA(x1, wrh[1], acc);
        acc = MFMA(x1, wrl[1], acc);

        float z0[4], z1[4];
#pragma unroll
        for (int r = 0; r < 4; ++r) {
            const float h = fmaxf(acc[r] + bv, 0.0f);
            z0[r] = h * vl0;
            z1[r] = h * vl1;
        }
#pragma unroll
        for (int m = 1; m < 16; m <<= 1) {
#pragma unroll
            for (int r = 0; r < 4; ++r) {
                z0[r] += __shfl_xor(z0[r], m);
                z1[r] += __shfl_xor(z1[r], m);
            }
        }
        if ((lane & 15) == 0) {
#pragma unroll
            for (int r = 0; r < 4; ++r) {
                sZ[par][wv][4 * g + r][0] = z0[r];
                sZ[par][wv][4 * g + r][1] = z1[r];
            }
        }
        __syncthreads();
        if (t < 16) {
            const long node = (long)rt * 16 + t;
            const float a = sZ[par][0][t][0] + sZ[par][1][t][0] +
                            sZ[par][2][t][0] + sZ[par][3][t][0];
            const float b = sZ[par][0][t][1] + sZ[par][1][t][1] +
                            sZ[par][2][t][1] + sZ[par][3][t][1];
            zm[node * 2 + 0] = a;
            zm[node * 2 + 1] = b;
        }
    }
}

// ---------------- customer dense: layer1 + (h_c @ Vr + meanz + bo) -> out ----------
__global__ __launch_bounds__(256) void densec_k(const unsigned short* __restrict__ meanx,
                                                const float* __restrict__ meanz,
                                                const unsigned short* __restrict__ xc,
                                                const float* __restrict__ Wl1,
                                                const float* __restrict__ Wr1,
                                                const float* __restrict__ b1,
                                                const float* __restrict__ Vr,
                                                const float* __restrict__ bo,
                                                float* __restrict__ out, int n_nodes) {
    __shared__ unsigned short sH[2][16][72];
    const int t = threadIdx.x;
    const int lane = t & 63;
    const int wv = t >> 6;
    const int col = wv * 16 + (lane & 15);
    const int g = lane >> 4;

    bf16x8 w1lh[2], w1ll[2], w1rh[2], w1rl[2];
    LOAD_W(Wl1, Wr1, col, g, w1lh, w1ll, w1rh, w1rl);
    const float bv1 = b1[col];
    bf16x8 vrh[2], vrl[2];
    LOAD_V(Vr, (lane & 15), g, vrh, vrl);
    const int oc = lane & 15;
    const float bo2 = (oc < 2) ? bo[oc] : 0.0f;

    const int nrt = n_nodes >> 4;
    int par = 0;
    for (int rt = blockIdx.x; rt < nrt; rt += gridDim.x, par ^= 1) {
        const long rowA = (long)rt * 16 + (lane & 15);
        const bf16x8 mx0 = *(const bf16x8*)(meanx + rowA * DF + 8 * g);
        const bf16x8 mx1 = *(const bf16x8*)(meanx + rowA * DF + 32 + 8 * g);
        const bf16x8 xc0 = *(const bf16x8*)(xc + rowA * DF + 8 * g);
        const bf16x8 xc1 = *(const bf16x8*)(xc + rowA * DF + 32 + 8 * g);
        float mzv[4];
        if (oc < 2) {
#pragma unroll
            for (int r = 0; r < 4; ++r)
                mzv[r] = meanz[((long)rt * 16 + 4 * g + r) * 2 + oc];
        }

        f32x4 acc = {0.f, 0.f, 0.f, 0.f};
        acc = MFMA(mx0, w1lh[0], acc);
        acc = MFMA(mx0, w1ll[0], acc);
        acc = MFMA(mx1, w1lh[1], acc);
        acc = MFMA(mx1, w1ll[1], acc);
        acc = MFMA(xc0, w1rh[0], acc);
        acc = MFMA(xc0, w1rl[0], acc);
        acc = MFMA(xc1, w1rh[1], acc);
        acc = MFMA(xc1, w1rl[1], acc);
#pragma unroll
        for (int r = 0; r < 4; ++r)
            sH[par][4 * g + r][col] = (unsigned short)bf16rn(fmaxf(acc[r] + bv1, 0.0f));
        __syncthreads();

        const bf16x8 hc0 = *(const bf16x8*)&sH[par][lane & 15][8 * g];
        const bf16x8 hc1 = *(const bf16x8*)&sH[par][lane & 15][32 + 8 * g];
        f32x4 a2 = {0.f, 0.f, 0.f, 0.f};
        a2 = MFMA(hc0, vrh[0], a2);
        a2 = MFMA(hc0, vrl[0], a2);
        a2 = MFMA(hc1, vrh[1], a2);
        a2 = MFMA(hc1, vrl[1], a2);
        if (oc < 2) {
#pragma unroll
            for (int r = 0; r < 4; ++r) {
                const long node = (long)rt * 16 + 4 * g + r;
                out[node * 2 + oc] = a2[r] + mzv[r] + bo2;
            }
        }
    }
}

extern "C" void kernel_launch(void* const* d_in, const int* in_sizes, int n_in,
                              void* d_out, int out_size, void* d_ws, size_t ws_size,
                              hipStream_t stream) {
    const float* x_c = (const float*)d_in[0];
    const float* x_m = (const float*)d_in[1];
    const int* cm_src = (const int*)d_in[2];
    const int* cm_dst = (const int*)d_in[3];
    const int* mc_src = (const int*)d_in[4];
    const int* mc_dst = (const int*)d_in[5];
    const float* Wl1_cm = (const float*)d_in[6];
    const float* Wr1_cm = (const float*)d_in[7];
    const float* b1_cm = (const float*)d_in[8];
    const float* Wl1_mc = (const float*)d_in[9];
    const float* Wr1_mc = (const float*)d_in[10];
    const float* b1_mc = (const float*)d_in[11];
    // layer-2 cm weights (d_in[12..14]) are dead: h2_m is unused in the reference
    const float* Wl2_mc = (const float*)d_in[15];
    const float* Wr2_mc = (const float*)d_in[16];
    const float* b2_mc = (const float*)d_in[17];
    const float* W_lin = (const float*)d_in[18];
    const float* b_lin = (const float*)d_in[19];
    float* out = (float*)d_out;

    // ---- workspace layout (~85 MB) ----
    unsigned short* up = (unsigned short*)d_ws;
    unsigned short* aggm16 = up;                        // NM*64
    unsigned short* xm16 = aggm16 + (long)NM * DF;      // NM*64
    unsigned short* xc16 = xm16 + (long)NM * DF;        // NC*64
    unsigned short* meanx16 = xc16 + (long)NC * DF;     // NC*64
    float* zm = (float*)(meanx16 + (long)NC * DF);      // NM*2
    float* meanz = zm + (long)NM * 2;                   // NC*2
    float* Vl = meanz + (long)NC * 2;                   // 64*16
    float* Vr = Vl + 64 * 16;                           // 64*16
    float* bo = Vr + 64 * 16;                           // 2 (+pad)
    int* ip = (int*)(bo + 4);

    int* startM = ip;                   // NM+1 (written by bp22)
    int* startC = startM + (NM + 1);    // NC+1 (written by bp22)
    int* cstartM = startC + (NC + 1);   // NBM+1
    int* cstartC = cstartM + (NBM + 1); // NBC+1
    int* ccurM = cstartC + (NBC + 1);   // NBM
    int* ccurC = ccurM + NBM;           // NBC
    int* totM = ccurC + NBC;            // NBM
    int* totC = totM + NBM;             // NBC
    int* pmM = totC + NBC;              // NSB*NBM
    int* pmC = pmM + NSB * NBM;         // NSB*NBC
    int* srt_cm = pmC + NSB * NBC;      // NE
    int* srt_mc = srt_cm + NE;          // NE
    int* bktM = srt_mc + NE;            // NE
    int* bktC = bktM + NE;              // NE

    // coarse hist + presplit + V-compose -> parallel reduce -> scan -> sort
    prep_k<<<2 * NSB + PSB + 1, 256, 0, stream>>>(cm_dst, mc_dst, pmM, pmC,
                                                  x_c, x_m, (u16x4*)xc16, (u16x4*)xm16,
                                                  Wl2_mc, Wr2_mc, b2_mc, W_lin, b_lin,
                                                  Vl, Vr, bo);
    cred2_k<<<NBM + NBC, 256, 0, stream>>>(pmM, pmC, totM, totC);
    cscan3_k<<<1, 256, 0, stream>>>(totM, totC, cstartM, cstartC, ccurM, ccurC);
    bsort2_k<<<2 * NSB, 256, 0, stream>>>(cm_src, cm_dst, mc_src, mc_dst,
                                          ccurM, ccurC, bktM, bktC);
    bp22_k<<<NBM + NBC, 256, 0, stream>>>(bktM, cstartM, startM, srt_cm,
                                          bktC, cstartC, startC, srt_mc);

    // layer 1 @ merchants: m-mean (bf16), then dense folded to z = h_m @ Vl (2 f32)
    agg16_k<<<NM / 16, 256, 0, stream>>>(xc16, startM, srt_cm, aggm16, NM);
    dense1nm_k<<<1024, 256, 0, stream>>>(aggm16, xm16, Wl1_cm, Wr1_cm, b1_cm,
                                         Vl, zm, NM);

    // customers: dual aggregation (x_m rows + z pairs) in one edge sweep
    aggc2_k<<<NC / 16, 256, 0, stream>>>(xm16, zm, startC, srt_mc,
                                         meanx16, meanz, NC);

    // customers: layer1 + folded layer2 (h_c @ Vr + meanz) -> out
    densec_k<<<2048, 256, 0, stream>>>(meanx16, meanz, xc16,
                                       Wl1_mc, Wr1_mc, b1_mc,
                                       Vr, bo, out, NC);
}

// Round 20
// 170.080 us; speedup vs baseline: 1.7461x; 1.0363x over previous
//
#include <hip/hip_runtime.h>

#define NC 200000
#define NM 50000
#define NE 1000000
#define DF 64   // feature dim (D == H == 64)

// per-side bucket geometry, balanced to ~5.1K edges/bucket on both sides
#define BSH_M 8
#define BW_M 256
#define NBM ((NM + BW_M - 1) >> BSH_M)   // 196 (cm: dst = merchants, deg ~20)
#define BSH_C 10
#define BW_C 1024
#define NBC ((NC + BW_C - 1) >> BSH_C)   // 196 (mc: dst = customers, deg ~5)
#define CH 4096                          // edges per chunk block
#define NSB ((NE + CH - 1) / CH)         // 245
#define PSB 1024                         // presplit blocks inside prep_k

typedef __attribute__((ext_vector_type(8))) short bf16x8;
typedef __attribute__((ext_vector_type(4))) float f32x4;
typedef __attribute__((ext_vector_type(4))) unsigned short u16x4;

// ---------------- round-to-nearest bf16 helpers ----------------
__device__ __forceinline__ short bf16rn(float x) {
    unsigned u = __builtin_bit_cast(unsigned, x);
    unsigned r = u + 0x7FFFu + ((u >> 16) & 1u);
    return (short)(r >> 16);
}
__device__ __forceinline__ float bf16f(short h) {
    unsigned u = ((unsigned)(unsigned short)h) << 16;
    return __builtin_bit_cast(float, u);
}
__device__ __forceinline__ void split8(const f32x4 u, const f32x4 v,
                                       bf16x8& hi, bf16x8& lo) {
#pragma unroll
    for (int b = 0; b < 4; ++b) {
        short h = bf16rn(u[b]);
        hi[b] = h;
        lo[b] = bf16rn(u[b] - bf16f(h));
    }
#pragma unroll
    for (int b = 0; b < 4; ++b) {
        short h = bf16rn(v[b]);
        hi[4 + b] = h;
        lo[4 + b] = bf16rn(v[b] - bf16f(h));
    }
}

// ---------------- wave-wide inclusive scan (64 lanes, no barriers) ----------------
__device__ __forceinline__ int wscan_incl(int v, int lane) {
#pragma unroll
    for (int off = 1; off < 64; off <<= 1) {
        int y = __shfl_up(v, off);
        if (lane >= off) v += y;
    }
    return v;
}

// ---- prep: coarse hists (no global atomics) + bf16 presplit + W_lin folding ------
__global__ __launch_bounds__(256) void prep_k(const int* __restrict__ cm_dst,
                                              const int* __restrict__ mc_dst,
                                              int* __restrict__ pmM,
                                              int* __restrict__ pmC,
                                              const float* __restrict__ x_c,
                                              const float* __restrict__ x_m,
                                              u16x4* __restrict__ xc16,
                                              u16x4* __restrict__ xm16,
                                              const float* __restrict__ Wl2,
                                              const float* __restrict__ Wr2,
                                              const float* __restrict__ b2,
                                              const float* __restrict__ Wlin,
                                              const float* __restrict__ blin,
                                              float* __restrict__ Vl,
                                              float* __restrict__ Vr,
                                              float* __restrict__ bo) {
    __shared__ int cnt[256];
    const int t = threadIdx.x;
    if (blockIdx.x < 2 * NSB) {
        const int side = (blockIdx.x >= NSB);
        const int blk = blockIdx.x - side * NSB;
        const int* dst = side ? mc_dst : cm_dst;
        int* pm = side ? pmC : pmM;
        const int nb = side ? NBC : NBM;
        const int bsh = side ? BSH_C : BSH_M;
        cnt[t] = 0;
        __syncthreads();
        const int e0 = blk * CH;
        const int n = min(CH, NE - e0);
        for (int i = t; i < n; i += 256) atomicAdd(&cnt[dst[e0 + i] >> bsh], 1);
        __syncthreads();
        if (t < nb) pm[(long)blk * nb + t] = cnt[t];
    } else if (blockIdx.x < 2 * NSB + PSB) {
        const int blk = blockIdx.x - 2 * NSB;
        const int NC4 = NC * (DF / 4);
        const int NT4 = (NC + NM) * (DF / 4);
        const int st = PSB * 256;
        for (int i = blk * 256 + t; i < NT4; i += st) {
            const bool isc = (i < NC4);
            const int j = isc ? i : i - NC4;
            const f32x4 v = isc ? ((const f32x4*)x_c)[j] : ((const f32x4*)x_m)[j];
            u16x4 o;
#pragma unroll
            for (int b = 0; b < 4; ++b) o[b] = (unsigned short)bf16rn(v[b]);
            if (isc) xc16[j] = o;
            else     xm16[j] = o;
        }
    } else {
        // compose Vl = Wl2@Wlin, Vr = Wr2@Wlin (64x2 padded to 64x16), bo = b2@Wlin+blin
        for (int i = t; i < 2 * 64 * 16; i += 256) {
            float* dst = (i < 1024) ? Vl : Vr;
            dst[i & 1023] = 0.0f;
        }
        __syncthreads();
        if (t < 128) {
            const int k = t >> 1, o = t & 1;
            float sl = 0.f, sr = 0.f;
            for (int j = 0; j < 64; ++j) {
                sl += Wl2[k * 64 + j] * Wlin[j * 2 + o];
                sr += Wr2[k * 64 + j] * Wlin[j * 2 + o];
            }
            Vl[k * 16 + o] = sl;
            Vr[k * 16 + o] = sr;
        }
        if (t < 2) {
            float s = blin[t];
            for (int j = 0; j < 64; ++j) s += b2[j] * Wlin[j * 2 + t];
            bo[t] = s;
        }
    }
}

// ---------------- coarse reduce: one block per bucket, parallel over partials ------
__global__ __launch_bounds__(256) void cred2_k(const int* __restrict__ pmM,
                                               const int* __restrict__ pmC,
                                               int* __restrict__ totM,
                                               int* __restrict__ totC) {
    __shared__ int red[256];
    const int side = (blockIdx.x >= NBM);
    const int b = blockIdx.x - side * NBM;
    const int* pm = side ? pmC : pmM;
    const int nb = side ? NBC : NBM;
    int* tot = side ? totC : totM;
    const int t = threadIdx.x;
    int s = 0;
    for (int i = t; i < NSB; i += 256) s += pm[(long)i * nb + b];
    red[t] = s;
    __syncthreads();
    for (int off = 128; off > 0; off >>= 1) {
        if (t < off) red[t] += red[t + off];
        __syncthreads();
    }
    if (t == 0) tot[b] = red[0];
}

// ---------------- coarse scan over 392 totals (one tiny block) ----------------
__global__ __launch_bounds__(256) void cscan3_k(const int* __restrict__ totM,
                                                const int* __restrict__ totC,
                                                int* __restrict__ cstartM,
                                                int* __restrict__ cstartC,
                                                int* __restrict__ ccurM,
                                                int* __restrict__ ccurC) {
    __shared__ int wsum[4];
    const int t = threadIdx.x, lane = t & 63, wv = t >> 6;
    int s = (t < NBM) ? totM[t] : 0;
    int incl = wscan_incl(s, lane);
    if (lane == 63) wsum[wv] = incl;
    __syncthreads();
    int wadd = 0;
#pragma unroll
    for (int w = 0; w < 4; ++w) wadd += (w < wv) ? wsum[w] : 0;
    const int tot = incl + wadd;
    if (t < NBM) { cstartM[t] = tot - s; ccurM[t] = tot - s; }
    if (t == NBM - 1) cstartM[NBM] = tot;
    __syncthreads();
    int s2 = (t < NBC) ? totC[t] : 0;
    int incl2 = wscan_incl(s2, lane);
    if (lane == 63) wsum[wv] = incl2;
    __syncthreads();
    int wadd2 = 0;
#pragma unroll
    for (int w = 0; w < 4; ++w) wadd2 += (w < wv) ? wsum[w] : 0;
    const int tot2 = incl2 + wadd2;
    if (t < NBC) { cstartC[t] = tot2 - s2; ccurC[t] = tot2 - s2; }
    if (t == NBC - 1) cstartC[NBC] = tot2;
}

// ---------------- bucket sort pass 1: reuses prep's per-chunk histogram ----------
__global__ __launch_bounds__(256) void bsort2_k(const int* __restrict__ cm_src,
                                                const int* __restrict__ cm_dst,
                                                const int* __restrict__ mc_src,
                                                const int* __restrict__ mc_dst,
                                                const int* __restrict__ pmM,
                                                const int* __restrict__ pmC,
                                                int* __restrict__ ccurM,
                                                int* __restrict__ ccurC,
                                                int* __restrict__ bktM,
                                                int* __restrict__ bktC) {
    __shared__ int cnt[256], pfx[256], gbase[256];
    __shared__ int wsum[4];
    __shared__ int stage[CH];
    const int side = (blockIdx.x >= NSB);
    const int blk = blockIdx.x - side * NSB;
    const int* src = side ? mc_src : cm_src;
    const int* dst = side ? mc_dst : cm_dst;
    const int* pm = side ? pmC : pmM;
    int* ccur = side ? ccurC : ccurM;
    int* bkt = side ? bktC : bktM;
    const int nb = side ? NBC : NBM;
    const int bsh = side ? BSH_C : BSH_M;
    const int bmask = (side ? BW_C : BW_M) - 1;

    const int t = threadIdx.x, lane = t & 63, wv = t >> 6;
    const int e0 = blk * CH;
    const int n = min(CH, NE - e0);
    // counts come from prep's pm — no re-histogramming
    const int myc = (t < nb) ? pm[(long)blk * nb + t] : 0;
    int incl = wscan_incl(myc, lane);
    if (lane == 63) wsum[wv] = incl;
    __syncthreads();
    int wadd = 0;
#pragma unroll
    for (int w = 0; w < 4; ++w) wadd += (w < wv) ? wsum[w] : 0;
    const int excl = wadd + incl - myc;
    if (t < nb && myc > 0) gbase[t] = atomicAdd(&ccur[t], myc);
    pfx[t] = excl;
    cnt[t] = 0;
    __syncthreads();
    for (int i = t; i < n; i += 256) {
        const int d = dst[e0 + i];
        const int b = d >> bsh;
        const int p = pfx[b] + atomicAdd(&cnt[b], 1);
        stage[p] = (src[e0 + i] << bsh) | (d & bmask);
    }
    __syncthreads();
    for (int b = wv; b < nb; b += 4) {
        const int c = cnt[b];
        if (c == 0) continue;
        const int gb = gbase[b], lo = pfx[b];
        for (int j = lane; j < c; j += 64) bkt[gb + j] = stage[lo + j];
    }
}

// ---------------- bucket sort pass 2 + fine-offset construction ----------------
__global__ __launch_bounds__(256) void bp22_k(const int* __restrict__ bktM,
                                              const int* __restrict__ cstartM,
                                              int* __restrict__ startM,
                                              int* __restrict__ srtM,
                                              const int* __restrict__ bktC,
                                              const int* __restrict__ cstartC,
                                              int* __restrict__ startC,
                                              int* __restrict__ srtC) {
    __shared__ int lcur[BW_C];   // max of the two widths
    __shared__ int wsum[4];
    const int side = (blockIdx.x >= NBM);
    const int blk = blockIdx.x - side * NBM;
    const int* bkt = side ? bktC : bktM;
    const int* cstart = side ? cstartC : cstartM;
    int* start = side ? startC : startM;
    int* srt = side ? srtC : srtM;
    const int n_nodes = side ? NC : NM;
    const int bw = side ? BW_C : BW_M;
    const int bsh = side ? BSH_C : BSH_M;
    const int base = blk << bsh;
    const int t = threadIdx.x, lane = t & 63, wv = t >> 6;

    const int e0 = cstart[blk];
    const int e1 = cstart[blk + 1];

    for (int i = t; i < bw; i += 256) lcur[i] = 0;
    __syncthreads();
    for (int e = e0 + t; e < e1; e += 256) atomicAdd(&lcur[bkt[e] & (bw - 1)], 1);
    __syncthreads();

    int c0 = 0, c1 = 0, c2 = 0, c3 = 0;
    const bool act = (4 * t < bw);
    if (act) {
        c0 = lcur[4 * t + 0]; c1 = lcur[4 * t + 1];
        c2 = lcur[4 * t + 2]; c3 = lcur[4 * t + 3];
    }
    const int local = c0 + c1 + c2 + c3;
    int incl = wscan_incl(local, lane);
    if (lane == 63) wsum[wv] = incl;
    __syncthreads();
    int wadd = 0;
#pragma unroll
    for (int w = 0; w < 4; ++w) wadd += (w < wv) ? wsum[w] : 0;
    const int p0 = e0 + wadd + incl - local;
    const int p1 = p0 + c0, p2 = p1 + c1, p3 = p2 + c2;
    if (act) {
        lcur[4 * t + 0] = p0;
        lcur[4 * t + 1] = p1;
        lcur[4 * t + 2] = p2;
        lcur[4 * t + 3] = p3;
        if (base + 4 * t + 0 < n_nodes) start[base + 4 * t + 0] = p0;
        if (base + 4 * t + 1 < n_nodes) start[base + 4 * t + 1] = p1;
        if (base + 4 * t + 2 < n_nodes) start[base + 4 * t + 2] = p2;
        if (base + 4 * t + 3 < n_nodes) start[base + 4 * t + 3] = p3;
    }
    if (t == 0 && base + bw >= n_nodes) start[n_nodes] = e1;
    __syncthreads();

    for (int e = e0 + t; e < e1; e += 256) {
        const int p = bkt[e];
        const int pos = atomicAdd(&lcur[p & (bw - 1)], 1);
        srt[pos] = p >> bsh;
    }
}

// ---------------- single-plane mean for one node (16-lane subgroup) ----------------
__device__ __forceinline__ void agg_node16(const unsigned short* __restrict__ xhi,
                                           const int* __restrict__ start,
                                           const int* __restrict__ srt,
                                           unsigned short* __restrict__ mean16,
                                           int n, int k4) {
    const int s0 = start[n], s1 = start[n + 1];
    f32x4 a0 = {0.f, 0.f, 0.f, 0.f}, a1 = {0.f, 0.f, 0.f, 0.f};
    f32x4 a2 = {0.f, 0.f, 0.f, 0.f}, a3 = {0.f, 0.f, 0.f, 0.f};
    int e = s0;
    for (; e + 3 < s1; e += 4) {
        const int i0 = srt[e + 0], i1 = srt[e + 1];
        const int i2 = srt[e + 2], i3 = srt[e + 3];
        const u16x4 v0 = *(const u16x4*)(xhi + (long)i0 * DF + k4);
        const u16x4 v1 = *(const u16x4*)(xhi + (long)i1 * DF + k4);
        const u16x4 v2 = *(const u16x4*)(xhi + (long)i2 * DF + k4);
        const u16x4 v3 = *(const u16x4*)(xhi + (long)i3 * DF + k4);
#pragma unroll
        for (int c = 0; c < 4; ++c) {
            a0[c] += bf16f((short)v0[c]);
            a1[c] += bf16f((short)v1[c]);
            a2[c] += bf16f((short)v2[c]);
            a3[c] += bf16f((short)v3[c]);
        }
    }
    for (; e < s1; ++e) {
        const int i0 = srt[e];
        const u16x4 v0 = *(const u16x4*)(xhi + (long)i0 * DF + k4);
#pragma unroll
        for (int c = 0; c < 4; ++c) a0[c] += bf16f((short)v0[c]);
    }
    const float inv = 1.0f / fmaxf((float)(s1 - s0), 1.0f);
    u16x4 o;
#pragma unroll
    for (int c = 0; c < 4; ++c)
        o[c] = (unsigned short)bf16rn(((a0[c] + a1[c]) + (a2[c] + a3[c])) * inv);
    *(u16x4*)(mean16 + (long)n * DF + k4) = o;
}

// ---------------- merged aggregation: cm-side (x_c) and mc-side (x_m) in one launch ----
__global__ __launch_bounds__(256) void aggall_k(const unsigned short* __restrict__ xc16,
                                                const int* __restrict__ startM,
                                                const int* __restrict__ srt_cm,
                                                unsigned short* __restrict__ aggm16,
                                                const unsigned short* __restrict__ xm16,
                                                const int* __restrict__ startC,
                                                const int* __restrict__ srt_mc,
                                                unsigned short* __restrict__ meanx16) {
    const int t = threadIdx.x;
    const int sg = t >> 4;
    const int k4 = (t & 15) * 4;
    if (blockIdx.x < NM / 16) {
        const int n = blockIdx.x * 16 + sg;
        agg_node16(xc16, startM, srt_cm, aggm16, n, k4);
    } else {
        const int n = (blockIdx.x - NM / 16) * 16 + sg;
        agg_node16(xm16, startC, srt_mc, meanx16, n, k4);
    }
}

// ---------------- z-mean over mc edges: one thread per customer node ----------------
__global__ __launch_bounds__(256) void aggz_k(const float2* __restrict__ zm,
                                              const int* __restrict__ start,
                                              const int* __restrict__ srt,
                                              float2* __restrict__ meanz, int n_nodes) {
    int n = blockIdx.x * blockDim.x + threadIdx.x;
    const int st = gridDim.x * blockDim.x;
    for (; n < n_nodes; n += st) {
        const int s0 = start[n], s1 = start[n + 1];
        float z0 = 0.f, z1 = 0.f, y0 = 0.f, y1 = 0.f;
        int e = s0;
        for (; e + 1 < s1; e += 2) {
            const float2 a = zm[srt[e]];
            const float2 b = zm[srt[e + 1]];
            z0 += a.x; z1 += a.y;
            y0 += b.x; y1 += b.y;
        }
        if (e < s1) {
            const float2 a = zm[srt[e]];
            z0 += a.x; z1 += a.y;
        }
        const float inv = 1.0f / fmaxf((float)(s1 - s0), 1.0f);
        float2 o = {(z0 + y0) * inv, (z1 + y1) * inv};
        meanz[n] = o;
    }
}

#define MFMA(a, b, c) __builtin_amdgcn_mfma_f32_16x16x32_bf16((a), (b), (c), 0, 0, 0)

#define LOAD_W(Wl, Wr, col, g, wlh, wll, wrh, wrl)          \
    do {                                                    \
        _Pragma("unroll")                                   \
        for (int q = 0; q < 2; ++q) {                       \
            f32x4 tl0, tl1, tr0, tr1;                       \
            _Pragma("unroll")                               \
            for (int b = 0; b < 4; ++b) {                   \
                int k = 32 * q + 8 * (g) + b;               \
                tl0[b] = (Wl)[k * DF + (col)];              \
                tr0[b] = (Wr)[k * DF + (col)];              \
                tl1[b] = (Wl)[(k + 4) * DF + (col)];        \
                tr1[b] = (Wr)[(k + 4) * DF + (col)];        \
            }                                               \
            split8(tl0, tl1, wlh[q], wll[q]);               \
            split8(tr0, tr1, wrh[q], wrl[q]);               \
        }                                                   \
    } while (0)

// single V matrix, stride 16 (composed 64x2-in-64x16)
#define LOAD_V(V, col, g, vh, vlo)                          \
    do {                                                    \
        _Pragma("unroll")                                   \
        for (int q = 0; q < 2; ++q) {                       \
            f32x4 t0, t1;                                   \
            _Pragma("unroll")                               \
            for (int b = 0; b < 4; ++b) {                   \
                int k = 32 * q + 8 * (g) + b;               \
                t0[b] = (V)[k * 16 + (col)];                \
                t1[b] = (V)[(k + 4) * 16 + (col)];          \
            }                                               \
            split8(t0, t1, vh[q], vlo[q]);                  \
        }                                                   \
    } while (0)

// ---------------- dense1 @ NM: z = relu(mean@Wl + xm@Wr + b) @ Vl (2 floats/node) ----
__global__ __launch_bounds__(256) void dense1nm_k(const unsigned short* __restrict__ mean16,
                                                  const unsigned short* __restrict__ xm16,
                                                  const float* __restrict__ Wl,
                                                  const float* __restrict__ Wr,
                                                  const float* __restrict__ bias,
                                                  const float* __restrict__ Vl,
                                                  float* __restrict__ zm,
                                                  int n_nodes) {
    __shared__ float sZ[2][4][16][2];
    const int t = threadIdx.x;
    const int lane = t & 63;
    const int wv = t >> 6;
    const int col = wv * 16 + (lane & 15);
    const int g = lane >> 4;

    bf16x8 wlh[2], wll[2], wrh[2], wrl[2];
    LOAD_W(Wl, Wr, col, g, wlh, wll, wrh, wrl);
    const float bv = bias[col];
    const float vl0 = Vl[col * 16 + 0];
    const float vl1 = Vl[col * 16 + 1];

    const int nrt = n_nodes >> 4;
    int par = 0;
    for (int rt = blockIdx.x; rt < nrt; rt += gridDim.x, par ^= 1) {
        const long rowA = (long)rt * 16 + (lane & 15);
        const bf16x8 m0 = *(const bf16x8*)(mean16 + rowA * DF + 8 * g);
        const bf16x8 m1 = *(const bf16x8*)(mean16 + rowA * DF + 32 + 8 * g);
        const bf16x8 x0 = *(const bf16x8*)(xm16 + rowA * DF + 8 * g);
        const bf16x8 x1 = *(const bf16x8*)(xm16 + rowA * DF + 32 + 8 * g);
        f32x4 acc = {0.f, 0.f, 0.f, 0.f};
        acc = MFMA(m0, wlh[0], acc);
        acc = MFMA(m0, wll[0], acc);
        acc = MFMA(m1, wlh[1], acc);
        acc = MFMA(m1, wll[1], acc);
        acc = MFMA(x0, wrh[0], acc);
        acc = MFMA(x0, wrl[0], acc);
        acc = MFMA(x1, wrh[1], acc);
        acc = MFMA(x1, wrl[1], acc);

        float z0[4], z1[4];
#pragma unroll
        for (int r = 0; r < 4; ++r) {
            const float h = fmaxf(acc[r] + bv, 0.0f);
            z0[r] = h * vl0;
            z1[r] = h * vl1;
        }
#pragma unroll
        for (int m = 1; m < 16; m <<= 1) {
#pragma unroll
            for (int r = 0; r < 4; ++r) {
                z0[r] += __shfl_xor(z0[r], m);
                z1[r] += __shfl_xor(z1[r], m);
            }
        }
        if ((lane & 15) == 0) {
#pragma unroll
            for (int r = 0; r < 4; ++r) {
                sZ[par][wv][4 * g + r][0] = z0[r];
                sZ[par][wv][4 * g + r][1] = z1[r];
            }
        }
        __syncthreads();
        if (t < 16) {
            const long node = (long)rt * 16 + t;
            const float a = sZ[par][0][t][0] + sZ[par][1][t][0] +
                            sZ[par][2][t][0] + sZ[par][3][t][0];
            const float b = sZ[par][0][t][1] + sZ[par][1][t][1] +
                            sZ[par][2][t][1] + sZ[par][3][t][1];
            zm[node * 2 + 0] = a;
            zm[node * 2 + 1] = b;
        }
    }
}

// ---------------- customer dense: layer1 + (h_c @ Vr + meanz + bo) -> out ----------
__global__ __launch_bounds__(256) void densec_k(const unsigned short* __restrict__ meanx,
                                                const float* __restrict__ meanz,
                                                const unsigned short* __restrict__ xc,
                                                const float* __restrict__ Wl1,
                                                const float* __restrict__ Wr1,
                                                const float* __restrict__ b1,
                                                const float* __restrict__ Vr,
                                                const float* __restrict__ bo,
                                                float* __restrict__ out, int n_nodes) {
    __shared__ unsigned short sH[2][16][72];
    const int t = threadIdx.x;
    const int lane = t & 63;
    const int wv = t >> 6;
    const int col = wv * 16 + (lane & 15);
    const int g = lane >> 4;

    bf16x8 w1lh[2], w1ll[2], w1rh[2], w1rl[2];
    LOAD_W(Wl1, Wr1, col, g, w1lh, w1ll, w1rh, w1rl);
    const float bv1 = b1[col];
    bf16x8 vrh[2], vrl[2];
    LOAD_V(Vr, (lane & 15), g, vrh, vrl);
    const int oc = lane & 15;
    const float bo2 = (oc < 2) ? bo[oc] : 0.0f;

    const int nrt = n_nodes >> 4;
    int par = 0;
    for (int rt = blockIdx.x; rt < nrt; rt += gridDim.x, par ^= 1) {
        const long rowA = (long)rt * 16 + (lane & 15);
        const bf16x8 mx0 = *(const bf16x8*)(meanx + rowA * DF + 8 * g);
        const bf16x8 mx1 = *(const bf16x8*)(meanx + rowA * DF + 32 + 8 * g);
        const bf16x8 xc0 = *(const bf16x8*)(xc + rowA * DF + 8 * g);
        const bf16x8 xc1 = *(const bf16x8*)(xc + rowA * DF + 32 + 8 * g);
        float mzv[4];
        if (oc < 2) {
#pragma unroll
            for (int r = 0; r < 4; ++r)
                mzv[r] = meanz[((long)rt * 16 + 4 * g + r) * 2 + oc];
        }

        f32x4 acc = {0.f, 0.f, 0.f, 0.f};
        acc = MFMA(mx0, w1lh[0], acc);
        acc = MFMA(mx0, w1ll[0], acc);
        acc = MFMA(mx1, w1lh[1], acc);
        acc = MFMA(mx1, w1ll[1], acc);
        acc = MFMA(xc0, w1rh[0], acc);
        acc = MFMA(xc0, w1rl[0], acc);
        acc = MFMA(xc1, w1rh[1], acc);
        acc = MFMA(xc1, w1rl[1], acc);
#pragma unroll
        for (int r = 0; r < 4; ++r)
            sH[par][4 * g + r][col] = (unsigned short)bf16rn(fmaxf(acc[r] + bv1, 0.0f));
        __syncthreads();

        const bf16x8 hc0 = *(const bf16x8*)&sH[par][lane & 15][8 * g];
        const bf16x8 hc1 = *(const bf16x8*)&sH[par][lane & 15][32 + 8 * g];
        f32x4 a2 = {0.f, 0.f, 0.f, 0.f};
        a2 = MFMA(hc0, vrh[0], a2);
        a2 = MFMA(hc0, vrl[0], a2);
        a2 = MFMA(hc1, vrh[1], a2);
        a2 = MFMA(hc1, vrl[1], a2);
        if (oc < 2) {
#pragma unroll
            for (int r = 0; r < 4; ++r) {
                const long node = (long)rt * 16 + 4 * g + r;
                out[node * 2 + oc] = a2[r] + mzv[r] + bo2;
            }
        }
    }
}

extern "C" void kernel_launch(void* const* d_in, const int* in_sizes, int n_in,
                              void* d_out, int out_size, void* d_ws, size_t ws_size,
                              hipStream_t stream) {
    const float* x_c = (const float*)d_in[0];
    const float* x_m = (const float*)d_in[1];
    const int* cm_src = (const int*)d_in[2];
    const int* cm_dst = (const int*)d_in[3];
    const int* mc_src = (const int*)d_in[4];
    const int* mc_dst = (const int*)d_in[5];
    const float* Wl1_cm = (const float*)d_in[6];
    const float* Wr1_cm = (const float*)d_in[7];
    const float* b1_cm = (const float*)d_in[8];
    const float* Wl1_mc = (const float*)d_in[9];
    const float* Wr1_mc = (const float*)d_in[10];
    const float* b1_mc = (const float*)d_in[11];
    // layer-2 cm weights (d_in[12..14]) are dead: h2_m is unused in the reference
    const float* Wl2_mc = (const float*)d_in[15];
    const float* Wr2_mc = (const float*)d_in[16];
    const float* b2_mc = (const float*)d_in[17];
    const float* W_lin = (const float*)d_in[18];
    const float* b_lin = (const float*)d_in[19];
    float* out = (float*)d_out;

    // ---- workspace layout (~85 MB) ----
    unsigned short* up = (unsigned short*)d_ws;
    unsigned short* aggm16 = up;                        // NM*64
    unsigned short* xm16 = aggm16 + (long)NM * DF;      // NM*64
    unsigned short* xc16 = xm16 + (long)NM * DF;        // NC*64
    unsigned short* meanx16 = xc16 + (long)NC * DF;     // NC*64
    float* zm = (float*)(meanx16 + (long)NC * DF);      // NM*2
    float* meanz = zm + (long)NM * 2;                   // NC*2
    float* Vl = meanz + (long)NC * 2;                   // 64*16
    float* Vr = Vl + 64 * 16;                           // 64*16
    float* bo = Vr + 64 * 16;                           // 2 (+pad)
    int* ip = (int*)(bo + 4);

    int* startM = ip;                   // NM+1 (written by bp22)
    int* startC = startM + (NM + 1);    // NC+1 (written by bp22)
    int* cstartM = startC + (NC + 1);   // NBM+1
    int* cstartC = cstartM + (NBM + 1); // NBC+1
    int* ccurM = cstartC + (NBC + 1);   // NBM
    int* ccurC = ccurM + NBM;           // NBC
    int* totM = ccurC + NBC;            // NBM
    int* totC = totM + NBM;             // NBC
    int* pmM = totC + NBC;              // NSB*NBM
    int* pmC = pmM + NSB * NBM;         // NSB*NBC
    int* srt_cm = pmC + NSB * NBC;      // NE
    int* srt_mc = srt_cm + NE;          // NE
    int* bktM = srt_mc + NE;            // NE
    int* bktC = bktM + NE;              // NE

    // coarse hist + presplit + V-compose -> parallel reduce -> scan -> sort
    prep_k<<<2 * NSB + PSB + 1, 256, 0, stream>>>(cm_dst, mc_dst, pmM, pmC,
                                                  x_c, x_m, (u16x4*)xc16, (u16x4*)xm16,
                                                  Wl2_mc, Wr2_mc, b2_mc, W_lin, b_lin,
                                                  Vl, Vr, bo);
    cred2_k<<<NBM + NBC, 256, 0, stream>>>(pmM, pmC, totM, totC);
    cscan3_k<<<1, 256, 0, stream>>>(totM, totC, cstartM, cstartC, ccurM, ccurC);
    bsort2_k<<<2 * NSB, 256, 0, stream>>>(cm_src, cm_dst, mc_src, mc_dst,
                                          pmM, pmC, ccurM, ccurC, bktM, bktC);
    bp22_k<<<NBM + NBC, 256, 0, stream>>>(bktM, cstartM, startM, srt_cm,
                                          bktC, cstartC, startC, srt_mc);

    // both row-gather means in ONE launch (independent work, fills the machine)
    aggall_k<<<NM / 16 + NC / 16, 256, 0, stream>>>(xc16, startM, srt_cm, aggm16,
                                                    xm16, startC, srt_mc, meanx16);

    // merchants: dense folded to z = h_m @ Vl (2 f32/node)
    dense1nm_k<<<1024, 256, 0, stream>>>(aggm16, xm16, Wl1_cm, Wr1_cm, b1_cm,
                                         Vl, zm, NM);

    // customers: z-mean (tiny broadcast gather)
    aggz_k<<<782, 256, 0, stream>>>((const float2*)zm, startC, srt_mc,
                                    (float2*)meanz, NC);

    // customers: layer1 + folded layer2 (h_c @ Vr + meanz) -> out
    densec_k<<<2048, 256, 0, stream>>>(meanx16, meanz, xc16,
                                       Wl1_mc, Wr1_mc, b1_mc,
                                       Vr, bo, out, NC);
}